// Round 13
// baseline (132.712 us; speedup 1.0000x reference)
//
#include <hip/hip_runtime.h>
#include <math.h>

#define Bb 8
#define NTt 100
#define NPp 300
#define Cc 92
#define Aa 64

// ---------- shared math helpers (f32, op-for-op like the reference) ----------

__device__ __forceinline__ void iou_giou_f(const float* bt, const float* bp,
                                           float& iou, float& giou) {
  float ay1 = bt[0], ax1 = bt[1], ay2 = bt[2], ax2 = bt[3];
  float by1 = bp[0], bx1 = bp[1], by2 = bp[2], bx2 = bp[3];
  float area_a = fmaxf(ay2 - ay1, 0.0f) * fmaxf(ax2 - ax1, 0.0f);
  float area_b = fmaxf(by2 - by1, 0.0f) * fmaxf(bx2 - bx1, 0.0f);
  float inter = fmaxf(fminf(ay2, by2) - fmaxf(ay1, by1), 0.0f) *
                fmaxf(fminf(ax2, bx2) - fmaxf(ax1, bx1), 0.0f);
  float un = area_a + area_b - inter;
  iou = (un > 0.0f) ? (inter / un) : 0.0f;
  float enc = fmaxf(fmaxf(ay2, by2) - fminf(ay1, by1), 0.0f) *
              fmaxf(fmaxf(ax2, bx2) - fminf(ax1, bx1), 0.0f);
  giou = iou - ((enc > 0.0f) ? ((enc - un) / enc) : 0.0f);
}

__device__ __forceinline__ float box_cost_f(const float* bt, const float* bp,
                                            float& iou_out) {
  float iou, giou;
  iou_giou_f(bt, bp, iou, giou);
  iou_out = iou;
  float l1 = (fabsf(bt[0] - bp[0]) + fabsf(bt[1] - bp[1]) +
              fabsf(bt[2] - bp[2]) + fabsf(bt[3] - bp[3])) * 0.25f;
  return 2.0f * (1.0f - giou) + 5.0f * l1;
}

// ---------- DPP helpers: wave64 f64 min (value only, fmin) ----------

template <int CTRL>
__device__ __forceinline__ void dpp_fmin64(double& val) {
  union DU { double d; int i[2]; };
  DU a; a.d = val;
  int lo = __builtin_amdgcn_update_dpp(a.i[0], a.i[0], CTRL, 0xF, 0xF, false);
  int hi = __builtin_amdgcn_update_dpp(a.i[1], a.i[1], CTRL, 0xF, 0xF, false);
  DU o; o.i[0] = lo; o.i[1] = hi;
  val = fmin(val, o.d);
}

template <int CTRL>
__device__ __forceinline__ void dpp_step8(double& a0, double& a1, double& a2,
                                          double& a3, double& a4, double& a5,
                                          double& a6, double& a7) {
  dpp_fmin64<CTRL>(a0); dpp_fmin64<CTRL>(a1); dpp_fmin64<CTRL>(a2);
  dpp_fmin64<CTRL>(a3); dpp_fmin64<CTRL>(a4); dpp_fmin64<CTRL>(a5);
  dpp_fmin64<CTRL>(a6); dpp_fmin64<CTRL>(a7);
}

__device__ __forceinline__ double lane63_bcast(double x) {
  union DU { double d; int i[2]; };
  DU w; w.d = x;
  DU r;
  r.i[0] = __builtin_amdgcn_readlane(w.i[0], 63);
  r.i[1] = __builtin_amdgcn_readlane(w.i[1], 63);
  return r.d;
}

__device__ __forceinline__ double wave_fmin64_bcast(double m01) {
  double mv = m01;
  dpp_fmin64<0x111>(mv);
  dpp_fmin64<0x112>(mv);
  dpp_fmin64<0x114>(mv);
  dpp_fmin64<0x118>(mv);
  dpp_fmin64<0x142>(mv);
  dpp_fmin64<0x143>(mv);
  return lane63_bcast(mv);
}

__device__ __forceinline__ double read_u_row(double u_lo, double u_hi, int i0u) {
  int ridx = i0u - 1;
  int src = ridx & 63;
  union DU { double d; int i[2]; };
  DU a, bb, r;
  a.d = u_lo; bb.d = u_hi;
  int lo0 = __builtin_amdgcn_readlane(a.i[0], src);
  int hi0 = __builtin_amdgcn_readlane(a.i[1], src);
  int lo1 = __builtin_amdgcn_readlane(bb.i[0], src);
  int hi1 = __builtin_amdgcn_readlane(bb.i[1], src);
  bool hih = (ridx >> 6) != 0;
  r.i[0] = hih ? lo1 : lo0;
  r.i[1] = hih ? hi1 : hi0;
  return r.d;
}

__device__ __forceinline__ int sel5(int s, int a0, int a1, int a2, int a3, int a4) {
  int r = a4;
  r = (s == 3) ? a3 : r;
  r = (s == 2) ? a2 : r;
  r = (s == 1) ? a1 : r;
  r = (s == 0) ? a0 : r;
  return r;
}

// ---------- K1: cls + match-cost, one wave per (b,t) row (800 blocks) ----------

__global__ void __launch_bounds__(64) cost_kernel(
    const float* __restrict__ category, const float* __restrict__ bbox,
    const float* __restrict__ box_preds, const float* __restrict__ cat_preds,
    float* __restrict__ cost, int* __restrict__ cls) {
  int bt = blockIdx.x;                 // 0..799
  int b = bt / NTt;
  int lane = threadIdx.x;

  const float* crow = category + (size_t)bt * Cc;
  float c0 = (lane < Cc) ? crow[lane] : 0.0f;
  float c1 = (lane < Cc - 64) ? crow[lane + 64] : 0.0f;
  unsigned long long m0 = __ballot(c0 == 1.0f);
  unsigned long long m1 = __ballot(c1 == 1.0f);
  int cl = m0 ? __builtin_ctzll(m0) : (m1 ? 64 + __builtin_ctzll(m1) : 0);
  if (lane == 0) cls[bt] = cl;

  float tb[4];
  tb[0] = bbox[(size_t)bt * 4 + 0];
  tb[1] = bbox[(size_t)bt * 4 + 1];
  tb[2] = bbox[(size_t)bt * 4 + 2];
  tb[3] = bbox[(size_t)bt * 4 + 3];

  const float4* bp4 = (const float4*)(box_preds + (size_t)b * NPp * 4);
  const float* cp = cat_preds + (size_t)b * NPp * Cc + cl;
  float* crow_out = cost + (size_t)bt * NPp;

  #pragma unroll
  for (int k = 0; k < 5; ++k) {
    int p = lane + (k << 6);
    if (p < NPp) {
      float4 bpv = bp4[p];
      float pb[4] = {bpv.x, bpv.y, bpv.z, bpv.w};
      float iou;
      float bc = box_cost_f(tb, pb, iou);
      float pc = cp[(size_t)p * Cc];
      crow_out[p] = (1.0f - pc) + bc;
    }
  }
}

// ---------- K2: LDS-staged JV, batch-8 fast path + SALU claim walk ----------
// Staging: 4 waves float4-copy n cost rows into LDS, waves 1-3 exit.
// JV on wave 0, exact reference trajectory. Fast path (iteration 1, u[i]=0):
// key[j] = (double)c[i][j] - v[j]; argmin occupancy-independent, claims never
// modify v => 8 rows precompute with 8 interleaved DPP chains. Column
// occupancy lives in 5 wave-UNIFORM 64-bit masks M[k] (bit L = col 5L+k+1
// occupied) so the claim walk is pure SALU - zero ballots in steady state;
// masks rebuilt (5 ballots) only after a fallback. First collision -> proven
// bit-exact Dijkstra fallback, batch restarts after it. Column map: lane L
// (<60) owns j = 5L+1..5L+5 (ctz-of-ballot = smallest j, np.argmin tie rule).

template <bool STAGE>
__global__ void __launch_bounds__(256, 1) jv_kernel(
    const int* __restrict__ num_objects, const float* __restrict__ cat_preds,
    const float* __restrict__ gcost, int* __restrict__ pj_g,
    double* __restrict__ partials, float* __restrict__ diag) {
  extern __shared__ char smem[];
  const int b = blockIdx.x;
  const int tid = threadIdx.x;
  const int lane = tid & 63;

  float* lds_cost = (float*)smem;
  const int n = num_objects[b];
  const float* costg = gcost + (size_t)b * NTt * NPp;

  if (STAGE) {
    const float4* s4 = (const float4*)costg;
    float4* d4 = (float4*)lds_cost;
    int n4 = n * (NPp / 4);
    for (int t = tid; t < n4; t += 256) d4[t] = s4[t];
  }
  __syncthreads();

  if (tid >= 64) return;     // waves 1-3 done; wave 0 runs JV barrier-free

  const float* costb = STAGE ? lds_cost : costg;

  long long t_jv0 = clock64();

  const double INF = __builtin_inf();
  const bool active = lane < 60;
  const int laneOff = active ? 5 * lane : 0;

  double v0 = 0.0, v1 = 0.0, v2 = 0.0, v3 = 0.0, v4 = 0.0;
  double u_lo = 0.0, u_hi = 0.0;                 // u[lane+1], u[lane+65]
  int wp0 = 0, wp1 = 0, wp2 = 0, wp3 = 0, wp4 = 0;   // (way<<7)|pj per slot
  unsigned long long M0 = 0, M1 = 0, M2 = 0, M3 = 0, M4 = 0;  // occupancy

  int i = 1;
  while (i <= n) {
    int cnt = n - i + 1; if (cnt > 8) cnt = 8;

    // ---- batch precompute: 8 local argmins ----
    double m[8]; int p01a[8];
    #pragma unroll
    for (int r = 0; r < 8; ++r) {
      int row = i + r; if (row > n) row = n;     // pad (result unused)
      const float* rowp = costb + (row - 1) * NPp + laneOff;
      float ca = rowp[0], cb2 = rowp[1], cc = rowp[2], cd = rowp[3], ce = rowp[4];
      double cv0 = active ? (double)ca - v0 : INF;
      double cv1 = active ? (double)cb2 - v1 : INF;
      double cv2 = active ? (double)cc - v2 : INF;
      double cv3 = active ? (double)cd - v3 : INF;
      double cv4 = active ? (double)ce - v4 : INF;
      double m01 = fmin(fmin(fmin(cv0, cv1), fmin(cv2, cv3)), cv4);
      int k0 = (cv3 == m01) ? 3 : 4;
      k0 = (cv2 == m01) ? 2 : k0;
      k0 = (cv1 == m01) ? 1 : k0;
      k0 = (cv0 == m01) ? 0 : k0;
      m[r] = m01;
      p01a[r] = laneOff + k0 + 1;
    }

    // ---- 8 interleaved DPP reduction chains ----
    double r0 = m[0], r1 = m[1], r2 = m[2], r3 = m[3],
           r4 = m[4], r5 = m[5], r6 = m[6], r7 = m[7];
    dpp_step8<0x111>(r0, r1, r2, r3, r4, r5, r6, r7);
    dpp_step8<0x112>(r0, r1, r2, r3, r4, r5, r6, r7);
    dpp_step8<0x114>(r0, r1, r2, r3, r4, r5, r6, r7);
    dpp_step8<0x118>(r0, r1, r2, r3, r4, r5, r6, r7);
    dpp_step8<0x142>(r0, r1, r2, r3, r4, r5, r6, r7);
    dpp_step8<0x143>(r0, r1, r2, r3, r4, r5, r6, r7);

    // ---- winner find per row (ballot + readlane) ----
    double dly[8]; int jw[8];
    {
      double rr[8] = {r0, r1, r2, r3, r4, r5, r6, r7};
      #pragma unroll
      for (int r = 0; r < 8; ++r) {
        double delta = lane63_bcast(rr[r]);
        unsigned long long hit = __ballot(m[r] == delta);
        int winlane = __builtin_ctzll(hit);
        dly[r] = delta;
        jw[r] = __builtin_amdgcn_readlane(p01a[r], winlane);
      }
    }

    // ---- SALU claim walk over uniform masks (no cross-lane ops) ----
    bool doclaim[8];
    int consumed = 0, fbrow = 0;
    bool stop = false;
    #pragma unroll
    for (int r = 0; r < 8; ++r) {
      doclaim[r] = false;
      if (r < cnt && !stop) {
        int jm = jw[r] - 1;
        int ow = jm / 5, sk = jm - 5 * (jm / 5);
        unsigned long long Ms = (sk == 0) ? M0 : (sk == 1) ? M1 :
                                (sk == 2) ? M2 : (sk == 3) ? M3 : M4;
        if ((Ms >> ow) & 1) {
          fbrow = i + r; stop = true;
        } else {
          if      (sk == 0) M0 |= 1ull << ow;
          else if (sk == 1) M1 |= 1ull << ow;
          else if (sk == 2) M2 |= 1ull << ow;
          else if (sk == 3) M3 |= 1ull << ow;
          else              M4 |= 1ull << ow;
          doclaim[r] = true;
          consumed = r + 1;
        }
      }
    }

    // ---- apply claims (per-lane predicated, no cross-lane) ----
    #pragma unroll
    for (int r = 0; r < 8; ++r) {
      if (doclaim[r]) {
        int row = i + r;
        int jm = jw[r] - 1;
        int ow = jm / 5, sk = jm - 5 * (jm / 5);
        if (lane == ow) {
          if      (sk == 0) wp0 = (wp0 & ~127) | row;
          else if (sk == 1) wp1 = (wp1 & ~127) | row;
          else if (sk == 2) wp2 = (wp2 & ~127) | row;
          else if (sk == 3) wp3 = (wp3 & ~127) | row;
          else              wp4 = (wp4 & ~127) | row;
        }
        int ridx = row - 1;
        if ((ridx & 63) == lane) {
          if (ridx >> 6) u_hi += dly[r]; else u_lo += dly[r];
        }
      }
    }

    // ---- fallback: full bit-exact Dijkstra for row fbrow ----
    if (fbrow) {
      double mv0 = INF, mv1 = INF, mv2 = INF, mv3 = INF, mv4 = INF;
      int usedmask = 0, uf = 0;
      int j0u = 0, i0u = fbrow;

      while (true) {
        { int ridx = i0u - 1; if ((ridx & 63) == lane) uf |= 1 << (ridx >> 6); }

        const float* rowp = costb + (i0u - 1) * NPp + laneOff;
        float fa = rowp[0], fb = rowp[1], fc = rowp[2], fd = rowp[3], fe = rowp[4];
        double ui0 = read_u_row(u_lo, u_hi, i0u);

        {
          double cur = (double)fa - ui0 - v0;
          wp0 = (cur < mv0) ? ((j0u << 7) | (wp0 & 127)) : wp0;
          mv0 = fmin(mv0, cur);
        }
        {
          double cur = (double)fb - ui0 - v1;
          wp1 = (cur < mv1) ? ((j0u << 7) | (wp1 & 127)) : wp1;
          mv1 = fmin(mv1, cur);
        }
        {
          double cur = (double)fc - ui0 - v2;
          wp2 = (cur < mv2) ? ((j0u << 7) | (wp2 & 127)) : wp2;
          mv2 = fmin(mv2, cur);
        }
        {
          double cur = (double)fd - ui0 - v3;
          wp3 = (cur < mv3) ? ((j0u << 7) | (wp3 & 127)) : wp3;
          mv3 = fmin(mv3, cur);
        }
        {
          double cur = (double)fe - ui0 - v4;
          wp4 = (cur < mv4) ? ((j0u << 7) | (wp4 & 127)) : wp4;
          mv4 = fmin(mv4, cur);
        }

        double dv0 = (!active || (usedmask & 1))  ? INF : mv0;
        double dv1 = (!active || (usedmask & 2))  ? INF : mv1;
        double dv2 = (!active || (usedmask & 4))  ? INF : mv2;
        double dv3 = (!active || (usedmask & 8))  ? INF : mv3;
        double dv4 = (!active || (usedmask & 16)) ? INF : mv4;

        double mm = fmin(fmin(fmin(dv0, dv1), fmin(dv2, dv3)), dv4);
        int kk = (dv3 == mm) ? 3 : 4;
        kk = (dv2 == mm) ? 2 : kk;
        kk = (dv1 == mm) ? 1 : kk;
        kk = (dv0 == mm) ? 0 : kk;
        int pl2 = sel5(kk, wp0 & 127, wp1 & 127, wp2 & 127, wp3 & 127, wp4 & 127);
        int pk2 = ((laneOff + kk + 1) << 7) | pl2;

        double delta2 = wave_fmin64_bcast(mm);
        unsigned long long hit2 = __ballot(mm == delta2);
        int winlane2 = __builtin_ctzll(hit2);
        int wpk2 = __builtin_amdgcn_readlane(pk2, winlane2);
        int j1b = wpk2 >> 7, i1b = wpk2 & 127;

        if (uf & 1) u_lo += delta2;
        if (uf & 2) u_hi += delta2;
        v0 -= (usedmask & 1)  ? delta2 : 0.0;
        v1 -= (usedmask & 2)  ? delta2 : 0.0;
        v2 -= (usedmask & 4)  ? delta2 : 0.0;
        v3 -= (usedmask & 8)  ? delta2 : 0.0;
        v4 -= (usedmask & 16) ? delta2 : 0.0;
        mv0 -= delta2; mv1 -= delta2; mv2 -= delta2; mv3 -= delta2; mv4 -= delta2;

        int jm = j1b - 1;
        int wl = jm / 5;
        int sk = jm - 5 * wl;
        if (lane == wl) {
          usedmask |= 1 << sk;
          if      (sk == 0) mv0 = -INF;
          else if (sk == 1) mv1 = -INF;
          else if (sk == 2) mv2 = -INF;
          else if (sk == 3) mv3 = -INF;
          else              mv4 = -INF;
        }

        j0u = j1b; i0u = i1b;
        if (i0u == 0) break;
      }

      // augment alternating path (uniform readlane walk)
      {
        int jj = j0u;
        int idx = jj - 1;
        int owner = idx / 5;
        int slot = idx - 5 * owner;
        int f0 = __builtin_amdgcn_readlane(wp0, owner),
            f1 = __builtin_amdgcn_readlane(wp1, owner),
            f2 = __builtin_amdgcn_readlane(wp2, owner),
            f3 = __builtin_amdgcn_readlane(wp3, owner),
            f4 = __builtin_amdgcn_readlane(wp4, owner);
        int wpv = sel5(slot, f0, f1, f2, f3, f4);
        int wayv = wpv >> 7;

        while (true) {
          int jp = wayv;                        // uniform
          int newv;
          int wayn = 0;
          if (jp != 0) {
            int idx2 = jp - 1;
            int owner2 = idx2 / 5;
            int slot2 = idx2 - 5 * owner2;
            int g0 = __builtin_amdgcn_readlane(wp0, owner2),
                g1 = __builtin_amdgcn_readlane(wp1, owner2),
                g2 = __builtin_amdgcn_readlane(wp2, owner2),
                g3 = __builtin_amdgcn_readlane(wp3, owner2),
                g4 = __builtin_amdgcn_readlane(wp4, owner2);
            int wpn = sel5(slot2, g0, g1, g2, g3, g4);
            wayn = wpn >> 7;
            newv = wpn & 127;                   // old pj[jp]
          } else {
            newv = fbrow;
          }
          if (lane == owner) {
            if      (slot == 0) wp0 = (wp0 & ~127) | newv;
            else if (slot == 1) wp1 = (wp1 & ~127) | newv;
            else if (slot == 2) wp2 = (wp2 & ~127) | newv;
            else if (slot == 3) wp3 = (wp3 & ~127) | newv;
            else                wp4 = (wp4 & ~127) | newv;
          }
          if (jp == 0) break;
          jj = jp;
          idx = jj - 1;
          owner = idx / 5;
          slot = idx - 5 * owner;
          wayv = wayn;
        }
      }

      // rebuild uniform occupancy masks from wp (only place ballots are used)
      M0 = __ballot((wp0 & 127) != 0);
      M1 = __ballot((wp1 & 127) != 0);
      M2 = __ballot((wp2 & 127) != 0);
      M3 = __ballot((wp3 & 127) != 0);
      M4 = __ballot((wp4 & 127) != 0);
    }

    i += consumed + (fbrow ? 1 : 0);
  }

  long long t_jv1 = clock64();

  // export assignment
  if (active) {
    int base = b * 304;
    pj_g[base + 5 * lane + 1] = wp0 & 127;
    pj_g[base + 5 * lane + 2] = wp1 & 127;
    pj_g[base + 5 * lane + 3] = wp2 & 127;
    pj_g[base + 5 * lane + 4] = wp3 & 127;
    pj_g[base + 5 * lane + 5] = wp4 & 127;
  }

  // num_predicted contribution: count cat_preds[b,1,:] < 0.5
  const float* cpb1 = cat_preds + ((size_t)b * NPp + 1) * Cc;
  float q0 = (lane < Cc) ? cpb1[lane] : 1.0f;
  float q1 = (lane + 64 < Cc) ? cpb1[lane + 64] : 1.0f;
  unsigned long long mm0 = __ballot(q0 < 0.5f);
  unsigned long long mm1 = __ballot(q1 < 0.5f);
  if (lane == 0) partials[b * 8 + 7] = (double)(__popcll(mm0) + __popcll(mm1));

  // diagnostic: JV-phase ticks -> WRITE_SIZE (64B lines of 4096-tick units)
  if (diag != nullptr && lane == 0) {
    int nl = (int)((t_jv1 - t_jv0) >> 12);
    if (nl > 256) nl = 256;
    for (int w2 = 0; w2 < nl; ++w2)
      __builtin_nontemporal_store(1.0f, diag + ((b << 12) + (w2 << 4)));
  }
}

// ---------- K3: per-column losses, one wave per (b,j) (2400 blocks) ----------

__global__ void __launch_bounds__(64) loss_kernel(
    const float* __restrict__ attribute, const float* __restrict__ bbox,
    const float* __restrict__ cat_preds, const float* __restrict__ attribute_preds,
    const float* __restrict__ box_preds, const int* __restrict__ gcls,
    const int* __restrict__ pj_g, double* __restrict__ colpart) {
  int gb = blockIdx.x;                 // b*NPp + j
  int b = gb / NPp;
  int j = gb - b * NPp;
  int lane = threadIdx.x;
  double* outp = colpart + (size_t)gb * 8;

  int prow = pj_g[b * 304 + j + 1];
  if (prow == 0) {
    if (lane < 8) outp[lane] = 0.0;
    return;
  }

  int t = prow - 1;
  int bt = b * NTt + t;

  const float EPSF = 1e-7f;
  const float HIF  = (float)(1.0 - 1e-7);

  // focal attribute term: lane a handles attribute a
  float y = attribute[(size_t)bt * Aa + lane];
  float p = fminf(fmaxf(attribute_preds[(size_t)gb * Aa + lane], EPSF), HIF);
  float ce = -(y * logf(p) + (1.0f - y) * logf(1.0f - p));
  float pt = y * p + (1.0f - y) * (1.0f - p);
  float alpha = y * 0.25f + (1.0f - y) * 0.75f;
  float om = 1.0f - pt;
  double sattr = (double)(alpha * (om * om) * ce);
  #pragma unroll
  for (int off = 32; off >= 1; off >>= 1) sattr += __shfl_xor(sattr, off);

  if (lane == 0) {
    int cl = gcls[bt];
    float pc = cat_preds[(size_t)gb * Cc + cl];
    double scat = (double)(-logf(pc + 1e-5f));

    const float* btp = bbox + (size_t)bt * 4;
    const float* bpp = box_preds + (size_t)gb * 4;
    float iou;
    float bc = box_cost_f(btp, bpp, iou);
    float ia = 1.0f - iou;

    double c50 = (ia >= 0.5f) ? 1.0 : 0.0;
    double call = 0.0;
    for (int rr = 50; rr < 100; rr += 5) {
      float thr = (float)((double)rr / 100.0);
      if (ia >= thr) call += 1.0;
    }

    float yp = 1.0f - cat_preds[(size_t)gb * Cc + 0];
    float pn = yp / yp;
    pn = fminf(fmaxf(pn, EPSF), HIF);
    double sex = (double)(-logf(pn));

    outp[0] = scat;
    outp[1] = sattr;
    outp[2] = (double)bc;
    outp[3] = (double)ia;
    outp[4] = sex;
    outp[5] = c50;
    outp[6] = call;
    outp[7] = 0.0;
  }
}

// ---------- K4: fixed-tree per-(b,q) sums (56 blocks x 64) ----------

__global__ void __launch_bounds__(64) combine1_kernel(
    const double* __restrict__ colpart, double* __restrict__ partials) {
  int bid = blockIdx.x;                // 0..55
  int b = bid / 7;
  int q = bid - b * 7;
  int lane = threadIdx.x;

  double s = 0.0;
  #pragma unroll
  for (int k = 0; k < 5; ++k) {
    int j = lane + (k << 6);
    if (j < NPp) s += colpart[((size_t)(b * NPp + j)) * 8 + q];
  }
  #pragma unroll
  for (int off = 32; off >= 1; off >>= 1) s += __shfl_xor(s, off);
  if (lane == 0) partials[b * 8 + q] = s;
}

// ---------- K5: final outputs ----------

__global__ void final_kernel(const double* __restrict__ partials,
                             const int* __restrict__ num_objects,
                             float* __restrict__ out) {
  if (threadIdx.x != 0) return;
  double t[8];
  #pragma unroll
  for (int q = 0; q < 8; ++q) t[q] = 0.0;
  for (int b = 0; b < Bb; ++b)
    for (int q = 0; q < 8; ++q) t[q] += partials[b * 8 + q];

  int s = 0;
  for (int b = 0; b < Bb; ++b) s += num_objects[b];
  float tno = (float)s;

  float category_cost  = (float)t[0] / tno;
  float attribute_cost = (float)t[1] / tno;
  float box_cost       = (float)t[2] / tno;
  float exist_loss     = (float)t[4] / (float)(Bb * NPp);
  float total = category_cost + attribute_cost + box_cost + exist_loss;
  float iou_metric = (float)t[3] / tno;
  float npredf = (float)t[7];
  float mAP50 = (float)t[5] / npredf;
  float m5095 = (float)t[6] / (npredf * 10.0f);

  out[0] = total;
  out[1] = category_cost;
  out[2] = attribute_cost;
  out[3] = box_cost;
  out[4] = exist_loss;
  out[5] = iou_metric;
  out[6] = mAP50;
  out[7] = m5095;
}

// ---------- launcher ----------

extern "C" void kernel_launch(void* const* d_in, const int* in_sizes, int n_in,
                              void* d_out, int out_size, void* d_ws, size_t ws_size,
                              hipStream_t stream) {
  const float* category        = (const float*)d_in[0];
  const float* attribute       = (const float*)d_in[1];
  const float* bbox            = (const float*)d_in[2];
  const int*   num_objects     = (const int*)d_in[3];
  const float* cat_preds       = (const float*)d_in[4];
  const float* attribute_preds = (const float*)d_in[5];
  const float* box_preds       = (const float*)d_in[6];
  float* out = (float*)d_out;

  // ws layout
  double* partials = (double*)d_ws;                         //       0 ..     512
  int*    gcls     = (int*)((char*)d_ws + 512);             //     512 ..    3712
  float*  gcost    = (float*)((char*)d_ws + 4096);          //    4096 ..  964096
  int*    pj_g     = (int*)((char*)d_ws + 964096);          //  964096 ..  973824
  double* colpart  = (double*)((char*)d_ws + 973824);       //  973824 .. 1127424

  const size_t DIAG_OFF = 1127424;
  float* diag = (ws_size >= DIAG_OFF + (size_t)8 * 16384)
                    ? (float*)((char*)d_ws + DIAG_OFF) : nullptr;

  cost_kernel<<<Bb * NTt, 64, 0, stream>>>(category, bbox, box_preds, cat_preds,
                                           gcost, gcls);

  const int STAGED_LDS = NTt * NPp * 4;                     // 120000
  hipError_t e = hipFuncSetAttribute(
      reinterpret_cast<const void*>(&jv_kernel<true>),
      hipFuncAttributeMaxDynamicSharedMemorySize, STAGED_LDS);
  if (e == hipSuccess) {
    jv_kernel<true><<<Bb, 256, STAGED_LDS, stream>>>(num_objects, cat_preds,
                                                     gcost, pj_g, partials, diag);
  } else {
    jv_kernel<false><<<Bb, 256, 0, stream>>>(num_objects, cat_preds,
                                             gcost, pj_g, partials, diag);
  }

  loss_kernel<<<Bb * NPp, 64, 0, stream>>>(attribute, bbox, cat_preds,
                                           attribute_preds, box_preds, gcls,
                                           pj_g, colpart);
  combine1_kernel<<<Bb * 7, 64, 0, stream>>>(colpart, partials);
  final_kernel<<<1, 64, 0, stream>>>(partials, num_objects, out);
}

// Round 14
// 108.227 us; speedup vs baseline: 1.2262x; 1.2262x over previous
//
#include <hip/hip_runtime.h>
#include <math.h>

#define Bb 8
#define NTt 100
#define NPp 300
#define Cc 92
#define Aa 64

// ---------- shared math helpers (f32, op-for-op like the reference) ----------

__device__ __forceinline__ void iou_giou_f(const float* bt, const float* bp,
                                           float& iou, float& giou) {
  float ay1 = bt[0], ax1 = bt[1], ay2 = bt[2], ax2 = bt[3];
  float by1 = bp[0], bx1 = bp[1], by2 = bp[2], bx2 = bp[3];
  float area_a = fmaxf(ay2 - ay1, 0.0f) * fmaxf(ax2 - ax1, 0.0f);
  float area_b = fmaxf(by2 - by1, 0.0f) * fmaxf(bx2 - bx1, 0.0f);
  float inter = fmaxf(fminf(ay2, by2) - fmaxf(ay1, by1), 0.0f) *
                fmaxf(fminf(ax2, bx2) - fmaxf(ax1, bx1), 0.0f);
  float un = area_a + area_b - inter;
  iou = (un > 0.0f) ? (inter / un) : 0.0f;
  float enc = fmaxf(fmaxf(ay2, by2) - fminf(ay1, by1), 0.0f) *
              fmaxf(fmaxf(ax2, bx2) - fminf(ax1, bx1), 0.0f);
  giou = iou - ((enc > 0.0f) ? ((enc - un) / enc) : 0.0f);
}

__device__ __forceinline__ float box_cost_f(const float* bt, const float* bp,
                                            float& iou_out) {
  float iou, giou;
  iou_giou_f(bt, bp, iou, giou);
  iou_out = iou;
  float l1 = (fabsf(bt[0] - bp[0]) + fabsf(bt[1] - bp[1]) +
              fabsf(bt[2] - bp[2]) + fabsf(bt[3] - bp[3])) * 0.25f;
  return 2.0f * (1.0f - giou) + 5.0f * l1;
}

// ---------- DPP helpers ----------

template <int CTRL>
__device__ __forceinline__ void dpp_fmin64(double& val) {
  union DU { double d; int i[2]; };
  DU a; a.d = val;
  int lo = __builtin_amdgcn_update_dpp(a.i[0], a.i[0], CTRL, 0xF, 0xF, false);
  int hi = __builtin_amdgcn_update_dpp(a.i[1], a.i[1], CTRL, 0xF, 0xF, false);
  DU o; o.i[0] = lo; o.i[1] = hi;
  val = fmin(val, o.d);
}

template <int CTRL>
__device__ __forceinline__ void dpp_step4(double& a, double& b, double& c, double& d) {
  dpp_fmin64<CTRL>(a); dpp_fmin64<CTRL>(b); dpp_fmin64<CTRL>(c); dpp_fmin64<CTRL>(d);
}

template <int CTRL>
__device__ __forceinline__ void dpp_umin32(unsigned int& val) {
  unsigned int o = (unsigned int)__builtin_amdgcn_update_dpp(
      (int)val, (int)val, CTRL, 0xF, 0xF, false);
  val = (o < val) ? o : val;
}

__device__ __forceinline__ unsigned int wave_umin32_bcast(unsigned int x) {
  dpp_umin32<0x111>(x);
  dpp_umin32<0x112>(x);
  dpp_umin32<0x114>(x);
  dpp_umin32<0x118>(x);
  dpp_umin32<0x142>(x);
  dpp_umin32<0x143>(x);
  return (unsigned int)__builtin_amdgcn_readlane((int)x, 63);
}

__device__ __forceinline__ double lane63_bcast(double x) {
  union DU { double d; int i[2]; };
  DU w; w.d = x;
  DU r;
  r.i[0] = __builtin_amdgcn_readlane(w.i[0], 63);
  r.i[1] = __builtin_amdgcn_readlane(w.i[1], 63);
  return r.d;
}

__device__ __forceinline__ double wave_fmin64_bcast(double m01) {
  double mv = m01;
  dpp_fmin64<0x111>(mv);
  dpp_fmin64<0x112>(mv);
  dpp_fmin64<0x114>(mv);
  dpp_fmin64<0x118>(mv);
  dpp_fmin64<0x142>(mv);
  dpp_fmin64<0x143>(mv);
  return lane63_bcast(mv);
}

__device__ __forceinline__ double read_u_row(double u_lo, double u_hi, int i0u) {
  int ridx = i0u - 1;
  int src = ridx & 63;
  union DU { double d; int i[2]; };
  DU a, bb, r;
  a.d = u_lo; bb.d = u_hi;
  int lo0 = __builtin_amdgcn_readlane(a.i[0], src);
  int hi0 = __builtin_amdgcn_readlane(a.i[1], src);
  int lo1 = __builtin_amdgcn_readlane(bb.i[0], src);
  int hi1 = __builtin_amdgcn_readlane(bb.i[1], src);
  bool hih = (ridx >> 6) != 0;
  r.i[0] = hih ? lo1 : lo0;
  r.i[1] = hih ? hi1 : hi0;
  return r.d;
}

__device__ __forceinline__ int sel5(int s, int a0, int a1, int a2, int a3, int a4) {
  int r = a4;
  r = (s == 3) ? a3 : r;
  r = (s == 2) ? a2 : r;
  r = (s == 1) ? a1 : r;
  r = (s == 0) ? a0 : r;
  return r;
}

// ---------- K1: cls + match-cost + per-row f32 (min, argmin) (800 blocks) ----------
// Exactness of the argmin export: cost >= 0 (all terms nonneg), so f32 bits are
// monotonic as u32. Stage 1: u32 DPP min of value-bits. Stage 2: lanes holding
// the min value contribute their smallest column index; u32 DPP min of indices
// gives the GLOBAL smallest column (np.argmin first-min rule). f32->f64 is
// injective & monotone, so this argmin equals the reference's f64 argmin at v=0.

__global__ void __launch_bounds__(64) cost_kernel(
    const float* __restrict__ category, const float* __restrict__ bbox,
    const float* __restrict__ box_preds, const float* __restrict__ cat_preds,
    float* __restrict__ cost, int* __restrict__ cls,
    float* __restrict__ rowminf, int* __restrict__ rowargj) {
  int bt = blockIdx.x;                 // 0..799
  int b = bt / NTt;
  int lane = threadIdx.x;

  const float* crow = category + (size_t)bt * Cc;
  float c0 = (lane < Cc) ? crow[lane] : 0.0f;
  float c1 = (lane < Cc - 64) ? crow[lane + 64] : 0.0f;
  unsigned long long m0 = __ballot(c0 == 1.0f);
  unsigned long long m1 = __ballot(c1 == 1.0f);
  int cl = m0 ? __builtin_ctzll(m0) : (m1 ? 64 + __builtin_ctzll(m1) : 0);
  if (lane == 0) cls[bt] = cl;

  float tb[4];
  tb[0] = bbox[(size_t)bt * 4 + 0];
  tb[1] = bbox[(size_t)bt * 4 + 1];
  tb[2] = bbox[(size_t)bt * 4 + 2];
  tb[3] = bbox[(size_t)bt * 4 + 3];

  const float4* bp4 = (const float4*)(box_preds + (size_t)b * NPp * 4);
  const float* cp = cat_preds + (size_t)b * NPp * Cc + cl;
  float* crow_out = cost + (size_t)bt * NPp;

  float lmin = __builtin_inff();
  int   larg = 0x7FFFFFFF;

  #pragma unroll
  for (int k = 0; k < 5; ++k) {
    int p = lane + (k << 6);
    if (p < NPp) {
      float4 bpv = bp4[p];
      float pb[4] = {bpv.x, bpv.y, bpv.z, bpv.w};
      float iou;
      float bc = box_cost_f(tb, pb, iou);
      float pc = cp[(size_t)p * Cc];
      float cv = (1.0f - pc) + bc;
      crow_out[p] = cv;
      if (cv < lmin) { lmin = cv; larg = p; }   // ascending p => first-min
    }
  }

  // stage 1: min of value bits (positive floats -> u32-monotonic)
  union FU { float f; unsigned int u; };
  FU fu; fu.f = lmin;
  unsigned int minbits = wave_umin32_bcast(fu.u);
  // stage 2: smallest column among lanes holding the min
  unsigned int cand = (fu.u == minbits) ? (unsigned int)larg : 0xFFFFFFFFu;
  unsigned int argj = wave_umin32_bcast(cand);

  if (lane == 0) {
    FU mb; mb.u = minbits;
    rowminf[bt] = mb.f;
    rowargj[bt] = (int)argj;
  }
}

// ---------- K2: LDS-staged JV with phase-A precomputed claims (8 blocks x 256) ----------
// Phase A (new): while v == 0 (i.e., before the first fallback), row i's exact
// iteration-1 result is the precomputed f32 (min, argmin). Walk rows in order:
// uniform-SALU occupancy test on 5 masks; on success claim (pj, u[i]=delta)
// with purely local predicated updates; on first collision stop. Phase B:
// R12's proven batch-4 fast path + bit-exact Dijkstra fallback, starting at
// the collided row (it re-detects the collision and runs the full loop).
// Column map: lane L (<60) owns j = 5L+1..5L+5.

template <bool STAGE>
__global__ void __launch_bounds__(256, 1) jv_kernel(
    const int* __restrict__ num_objects, const float* __restrict__ cat_preds,
    const float* __restrict__ gcost, const float* __restrict__ rowminf,
    const int* __restrict__ rowargj, int* __restrict__ pj_g,
    double* __restrict__ partials) {
  extern __shared__ char smem[];
  const int b = blockIdx.x;
  const int tid = threadIdx.x;
  const int lane = tid & 63;

  float* lds_cost = (float*)smem;
  const int n = num_objects[b];
  const float* costg = gcost + (size_t)b * NTt * NPp;

  if (STAGE) {
    const float4* s4 = (const float4*)costg;
    float4* d4 = (float4*)lds_cost;
    int n4 = n * (NPp / 4);
    for (int t = tid; t < n4; t += 256) d4[t] = s4[t];
  }
  __syncthreads();

  if (tid >= 64) return;     // waves 1-3 done; wave 0 runs JV barrier-free

  const float* costb = STAGE ? lds_cost : costg;

  const double INF = __builtin_inf();
  const bool active = lane < 60;
  const int laneOff = active ? 5 * lane : 0;

  double v0 = 0.0, v1 = 0.0, v2 = 0.0, v3 = 0.0, v4 = 0.0;
  double u_lo = 0.0, u_hi = 0.0;                 // u[lane+1], u[lane+65]
  int wp0 = 0, wp1 = 0, wp2 = 0, wp3 = 0, wp4 = 0;   // (way<<7)|pj per slot
  int occm = 0;                                  // 5-bit occupancy of my cols

  // ---- phase A: precomputed claims while v == 0 ----
  // lane (r-1)&63 holds row r's (minf, argj); set 0 for rows 1..64, set 1 beyond.
  float mf0 = (lane < n) ? rowminf[b * NTt + lane] : 0.0f;
  int   aj0 = (lane < n) ? rowargj[b * NTt + lane] : 0;
  float mf1 = (lane + 64 < n) ? rowminf[b * NTt + lane + 64] : 0.0f;
  int   aj1 = (lane + 64 < n) ? rowargj[b * NTt + lane + 64] : 0;

  unsigned long long M0 = 0, M1 = 0, M2 = 0, M3 = 0, M4 = 0;  // uniform masks
  int i = 1;
  while (i <= n) {
    int ridx = i - 1;
    int j1 = (ridx >> 6) ? __builtin_amdgcn_readlane(aj1, ridx & 63)
                         : __builtin_amdgcn_readlane(aj0, ridx & 63);
    int ow = j1 / 5, sk = j1 - 5 * (j1 / 5);     // j1 is 0-based column
    unsigned long long Ms = (sk == 0) ? M0 : (sk == 1) ? M1 :
                            (sk == 2) ? M2 : (sk == 3) ? M3 : M4;
    if ((Ms >> ow) & 1) break;                   // collision -> phase B
    if      (sk == 0) M0 |= 1ull << ow;
    else if (sk == 1) M1 |= 1ull << ow;
    else if (sk == 2) M2 |= 1ull << ow;
    else if (sk == 3) M3 |= 1ull << ow;
    else              M4 |= 1ull << ow;
    if (lane == ow) {
      occm |= 1 << sk;
      if      (sk == 0) wp0 = (wp0 & ~127) | i;
      else if (sk == 1) wp1 = (wp1 & ~127) | i;
      else if (sk == 2) wp2 = (wp2 & ~127) | i;
      else if (sk == 3) wp3 = (wp3 & ~127) | i;
      else              wp4 = (wp4 & ~127) | i;
    }
    if ((ridx & 63) == lane) {                   // u-holder == data-holder lane
      if (ridx >> 6) u_hi += (double)mf1; else u_lo += (double)mf0;
    }
    ++i;
  }

  // ---- phase B: R12 batch-4 fast path + bit-exact Dijkstra fallback ----
  while (i <= n) {
    int cnt = n - i + 1; if (cnt > 4) cnt = 4;

    double m[4]; int p01a[4];
    #pragma unroll
    for (int r = 0; r < 4; ++r) {
      int row = i + r; if (row > n) row = n;     // pad (result unused)
      const float* rowp = costb + (row - 1) * NPp + laneOff;
      float ca = rowp[0], cb2 = rowp[1], cc = rowp[2], cd = rowp[3], ce = rowp[4];
      double cv0 = active ? (double)ca - v0 : INF;
      double cv1 = active ? (double)cb2 - v1 : INF;
      double cv2 = active ? (double)cc - v2 : INF;
      double cv3 = active ? (double)cd - v3 : INF;
      double cv4 = active ? (double)ce - v4 : INF;
      double m01 = fmin(fmin(fmin(cv0, cv1), fmin(cv2, cv3)), cv4);
      int k0 = (cv3 == m01) ? 3 : 4;
      k0 = (cv2 == m01) ? 2 : k0;
      k0 = (cv1 == m01) ? 1 : k0;
      k0 = (cv0 == m01) ? 0 : k0;
      m[r] = m01;
      p01a[r] = laneOff + k0 + 1;
    }
    double r0 = m[0], r1 = m[1], r2 = m[2], r3 = m[3];
    dpp_step4<0x111>(r0, r1, r2, r3);
    dpp_step4<0x112>(r0, r1, r2, r3);
    dpp_step4<0x114>(r0, r1, r2, r3);
    dpp_step4<0x118>(r0, r1, r2, r3);
    dpp_step4<0x142>(r0, r1, r2, r3);
    dpp_step4<0x143>(r0, r1, r2, r3);
    double dly[4]; int jw[4];
    {
      double rr[4] = {r0, r1, r2, r3};
      #pragma unroll
      for (int r = 0; r < 4; ++r) {
        double delta = lane63_bcast(rr[r]);
        unsigned long long hit = __ballot(m[r] == delta);
        int winlane = __builtin_ctzll(hit);
        dly[r] = delta;
        jw[r] = __builtin_amdgcn_readlane(p01a[r], winlane);
      }
    }

    int consumed = 0, fbrow = 0;
    #pragma unroll
    for (int r = 0; r < 4; ++r) {
      if (r < cnt && fbrow == 0) {
        int row = i + r;
        int j1 = jw[r];
        int jm = j1 - 1, ow = jm / 5, sk = jm - 5 * (jm / 5);
        unsigned long long mset = __ballot((occm >> sk) & 1);
        bool occ = (mset >> ow) & 1;
        consumed = r + 1;
        if (!occ) {
          if (lane == ow) {
            occm |= 1 << sk;
            if      (sk == 0) wp0 = (wp0 & ~127) | row;
            else if (sk == 1) wp1 = (wp1 & ~127) | row;
            else if (sk == 2) wp2 = (wp2 & ~127) | row;
            else if (sk == 3) wp3 = (wp3 & ~127) | row;
            else              wp4 = (wp4 & ~127) | row;
          }
          int ridx = row - 1;
          if ((ridx & 63) == lane) {
            if (ridx >> 6) u_hi += dly[r]; else u_lo += dly[r];
          }
        } else {
          fbrow = row;           // fast attempt had zero side effects
        }
      }
    }

    if (fbrow) {
      double mv0 = INF, mv1 = INF, mv2 = INF, mv3 = INF, mv4 = INF;
      int usedmask = 0, uf = 0;
      int j0u = 0, i0u = fbrow;

      while (true) {
        { int ridx = i0u - 1; if ((ridx & 63) == lane) uf |= 1 << (ridx >> 6); }

        const float* rowp = costb + (i0u - 1) * NPp + laneOff;
        float fa = rowp[0], fb = rowp[1], fc = rowp[2], fd = rowp[3], fe = rowp[4];
        double ui0 = read_u_row(u_lo, u_hi, i0u);

        {
          double cur = (double)fa - ui0 - v0;
          wp0 = (cur < mv0) ? ((j0u << 7) | (wp0 & 127)) : wp0;
          mv0 = fmin(mv0, cur);
        }
        {
          double cur = (double)fb - ui0 - v1;
          wp1 = (cur < mv1) ? ((j0u << 7) | (wp1 & 127)) : wp1;
          mv1 = fmin(mv1, cur);
        }
        {
          double cur = (double)fc - ui0 - v2;
          wp2 = (cur < mv2) ? ((j0u << 7) | (wp2 & 127)) : wp2;
          mv2 = fmin(mv2, cur);
        }
        {
          double cur = (double)fd - ui0 - v3;
          wp3 = (cur < mv3) ? ((j0u << 7) | (wp3 & 127)) : wp3;
          mv3 = fmin(mv3, cur);
        }
        {
          double cur = (double)fe - ui0 - v4;
          wp4 = (cur < mv4) ? ((j0u << 7) | (wp4 & 127)) : wp4;
          mv4 = fmin(mv4, cur);
        }

        double dv0 = (!active || (usedmask & 1))  ? INF : mv0;
        double dv1 = (!active || (usedmask & 2))  ? INF : mv1;
        double dv2 = (!active || (usedmask & 4))  ? INF : mv2;
        double dv3 = (!active || (usedmask & 8))  ? INF : mv3;
        double dv4 = (!active || (usedmask & 16)) ? INF : mv4;

        double mm = fmin(fmin(fmin(dv0, dv1), fmin(dv2, dv3)), dv4);
        int kk = (dv3 == mm) ? 3 : 4;
        kk = (dv2 == mm) ? 2 : kk;
        kk = (dv1 == mm) ? 1 : kk;
        kk = (dv0 == mm) ? 0 : kk;
        int pl2 = sel5(kk, wp0 & 127, wp1 & 127, wp2 & 127, wp3 & 127, wp4 & 127);
        int pk2 = ((laneOff + kk + 1) << 7) | pl2;

        double delta2 = wave_fmin64_bcast(mm);
        unsigned long long hit2 = __ballot(mm == delta2);
        int winlane2 = __builtin_ctzll(hit2);
        int wpk2 = __builtin_amdgcn_readlane(pk2, winlane2);
        int j1b = wpk2 >> 7, i1b = wpk2 & 127;

        if (uf & 1) u_lo += delta2;
        if (uf & 2) u_hi += delta2;
        v0 -= (usedmask & 1)  ? delta2 : 0.0;
        v1 -= (usedmask & 2)  ? delta2 : 0.0;
        v2 -= (usedmask & 4)  ? delta2 : 0.0;
        v3 -= (usedmask & 8)  ? delta2 : 0.0;
        v4 -= (usedmask & 16) ? delta2 : 0.0;
        mv0 -= delta2; mv1 -= delta2; mv2 -= delta2; mv3 -= delta2; mv4 -= delta2;

        int jm = j1b - 1;
        int wl = jm / 5;
        int sk = jm - 5 * wl;
        if (lane == wl) {
          usedmask |= 1 << sk;
          if      (sk == 0) mv0 = -INF;
          else if (sk == 1) mv1 = -INF;
          else if (sk == 2) mv2 = -INF;
          else if (sk == 3) mv3 = -INF;
          else              mv4 = -INF;
        }

        j0u = j1b; i0u = i1b;
        if (i0u == 0) break;
      }

      // augment alternating path (uniform readlane walk)
      {
        int jj = j0u;
        int idx = jj - 1;
        int owner = idx / 5;
        int slot = idx - 5 * owner;
        int f0 = __builtin_amdgcn_readlane(wp0, owner),
            f1 = __builtin_amdgcn_readlane(wp1, owner),
            f2 = __builtin_amdgcn_readlane(wp2, owner),
            f3 = __builtin_amdgcn_readlane(wp3, owner),
            f4 = __builtin_amdgcn_readlane(wp4, owner);
        int wpv = sel5(slot, f0, f1, f2, f3, f4);
        int wayv = wpv >> 7;

        while (true) {
          int jp = wayv;                        // uniform
          int newv;
          int wayn = 0;
          if (jp != 0) {
            int idx2 = jp - 1;
            int owner2 = idx2 / 5;
            int slot2 = idx2 - 5 * owner2;
            int g0 = __builtin_amdgcn_readlane(wp0, owner2),
                g1 = __builtin_amdgcn_readlane(wp1, owner2),
                g2 = __builtin_amdgcn_readlane(wp2, owner2),
                g3 = __builtin_amdgcn_readlane(wp3, owner2),
                g4 = __builtin_amdgcn_readlane(wp4, owner2);
            int wpn = sel5(slot2, g0, g1, g2, g3, g4);
            wayn = wpn >> 7;
            newv = wpn & 127;                   // old pj[jp]
          } else {
            newv = fbrow;
          }
          if (lane == owner) {
            if      (slot == 0) wp0 = (wp0 & ~127) | newv;
            else if (slot == 1) wp1 = (wp1 & ~127) | newv;
            else if (slot == 2) wp2 = (wp2 & ~127) | newv;
            else if (slot == 3) wp3 = (wp3 & ~127) | newv;
            else                wp4 = (wp4 & ~127) | newv;
          }
          if (jp == 0) break;
          jj = jp;
          idx = jj - 1;
          owner = idx / 5;
          slot = idx - 5 * owner;
          wayv = wayn;
        }
      }

      // refresh per-lane occupancy from wp
      occm = ((wp0 & 127) ? 1 : 0) | ((wp1 & 127) ? 2 : 0) |
             ((wp2 & 127) ? 4 : 0) | ((wp3 & 127) ? 8 : 0) |
             ((wp4 & 127) ? 16 : 0);
    }

    i += consumed;
  }

  // export assignment
  if (active) {
    int base = b * 304;
    pj_g[base + 5 * lane + 1] = wp0 & 127;
    pj_g[base + 5 * lane + 2] = wp1 & 127;
    pj_g[base + 5 * lane + 3] = wp2 & 127;
    pj_g[base + 5 * lane + 4] = wp3 & 127;
    pj_g[base + 5 * lane + 5] = wp4 & 127;
  }

  // num_predicted contribution: count cat_preds[b,1,:] < 0.5
  const float* cpb1 = cat_preds + ((size_t)b * NPp + 1) * Cc;
  float q0 = (lane < Cc) ? cpb1[lane] : 1.0f;
  float q1 = (lane + 64 < Cc) ? cpb1[lane + 64] : 1.0f;
  unsigned long long mm0 = __ballot(q0 < 0.5f);
  unsigned long long mm1 = __ballot(q1 < 0.5f);
  if (lane == 0) partials[b * 8 + 7] = (double)(__popcll(mm0) + __popcll(mm1));
}

// ---------- K3: per-column losses, one wave per (b,j) (2400 blocks) ----------

__global__ void __launch_bounds__(64) loss_kernel(
    const float* __restrict__ attribute, const float* __restrict__ bbox,
    const float* __restrict__ cat_preds, const float* __restrict__ attribute_preds,
    const float* __restrict__ box_preds, const int* __restrict__ gcls,
    const int* __restrict__ pj_g, double* __restrict__ colpart) {
  int gb = blockIdx.x;                 // b*NPp + j
  int b = gb / NPp;
  int j = gb - b * NPp;
  int lane = threadIdx.x;
  double* outp = colpart + (size_t)gb * 8;

  int prow = pj_g[b * 304 + j + 1];
  if (prow == 0) {
    if (lane < 8) outp[lane] = 0.0;
    return;
  }

  int t = prow - 1;
  int bt = b * NTt + t;

  const float EPSF = 1e-7f;
  const float HIF  = (float)(1.0 - 1e-7);

  float y = attribute[(size_t)bt * Aa + lane];
  float p = fminf(fmaxf(attribute_preds[(size_t)gb * Aa + lane], EPSF), HIF);
  float ce = -(y * logf(p) + (1.0f - y) * logf(1.0f - p));
  float pt = y * p + (1.0f - y) * (1.0f - p);
  float alpha = y * 0.25f + (1.0f - y) * 0.75f;
  float om = 1.0f - pt;
  double sattr = (double)(alpha * (om * om) * ce);
  #pragma unroll
  for (int off = 32; off >= 1; off >>= 1) sattr += __shfl_xor(sattr, off);

  if (lane == 0) {
    int cl = gcls[bt];
    float pc = cat_preds[(size_t)gb * Cc + cl];
    double scat = (double)(-logf(pc + 1e-5f));

    const float* btp = bbox + (size_t)bt * 4;
    const float* bpp = box_preds + (size_t)gb * 4;
    float iou;
    float bc = box_cost_f(btp, bpp, iou);
    float ia = 1.0f - iou;

    double c50 = (ia >= 0.5f) ? 1.0 : 0.0;
    double call = 0.0;
    for (int rr = 50; rr < 100; rr += 5) {
      float thr = (float)((double)rr / 100.0);
      if (ia >= thr) call += 1.0;
    }

    float yp = 1.0f - cat_preds[(size_t)gb * Cc + 0];
    float pn = yp / yp;
    pn = fminf(fmaxf(pn, EPSF), HIF);
    double sex = (double)(-logf(pn));

    outp[0] = scat;
    outp[1] = sattr;
    outp[2] = (double)bc;
    outp[3] = (double)ia;
    outp[4] = sex;
    outp[5] = c50;
    outp[6] = call;
    outp[7] = 0.0;
  }
}

// ---------- K4: fixed-tree per-(b,q) sums (56 blocks x 64) ----------

__global__ void __launch_bounds__(64) combine1_kernel(
    const double* __restrict__ colpart, double* __restrict__ partials) {
  int bid = blockIdx.x;                // 0..55
  int b = bid / 7;
  int q = bid - b * 7;
  int lane = threadIdx.x;

  double s = 0.0;
  #pragma unroll
  for (int k = 0; k < 5; ++k) {
    int j = lane + (k << 6);
    if (j < NPp) s += colpart[((size_t)(b * NPp + j)) * 8 + q];
  }
  #pragma unroll
  for (int off = 32; off >= 1; off >>= 1) s += __shfl_xor(s, off);
  if (lane == 0) partials[b * 8 + q] = s;
}

// ---------- K5: final outputs ----------

__global__ void final_kernel(const double* __restrict__ partials,
                             const int* __restrict__ num_objects,
                             float* __restrict__ out) {
  if (threadIdx.x != 0) return;
  double t[8];
  #pragma unroll
  for (int q = 0; q < 8; ++q) t[q] = 0.0;
  for (int b = 0; b < Bb; ++b)
    for (int q = 0; q < 8; ++q) t[q] += partials[b * 8 + q];

  int s = 0;
  for (int b = 0; b < Bb; ++b) s += num_objects[b];
  float tno = (float)s;

  float category_cost  = (float)t[0] / tno;
  float attribute_cost = (float)t[1] / tno;
  float box_cost       = (float)t[2] / tno;
  float exist_loss     = (float)t[4] / (float)(Bb * NPp);
  float total = category_cost + attribute_cost + box_cost + exist_loss;
  float iou_metric = (float)t[3] / tno;
  float npredf = (float)t[7];
  float mAP50 = (float)t[5] / npredf;
  float m5095 = (float)t[6] / (npredf * 10.0f);

  out[0] = total;
  out[1] = category_cost;
  out[2] = attribute_cost;
  out[3] = box_cost;
  out[4] = exist_loss;
  out[5] = iou_metric;
  out[6] = mAP50;
  out[7] = m5095;
}

// ---------- launcher ----------

extern "C" void kernel_launch(void* const* d_in, const int* in_sizes, int n_in,
                              void* d_out, int out_size, void* d_ws, size_t ws_size,
                              hipStream_t stream) {
  const float* category        = (const float*)d_in[0];
  const float* attribute       = (const float*)d_in[1];
  const float* bbox            = (const float*)d_in[2];
  const int*   num_objects     = (const int*)d_in[3];
  const float* cat_preds       = (const float*)d_in[4];
  const float* attribute_preds = (const float*)d_in[5];
  const float* box_preds       = (const float*)d_in[6];
  float* out = (float*)d_out;

  // ws layout
  double* partials = (double*)d_ws;                         //       0 ..     512
  int*    gcls     = (int*)((char*)d_ws + 512);             //     512 ..    3712
  float*  gcost    = (float*)((char*)d_ws + 4096);          //    4096 ..  964096
  int*    pj_g     = (int*)((char*)d_ws + 964096);          //  964096 ..  973824
  double* colpart  = (double*)((char*)d_ws + 973824);       //  973824 .. 1127424
  float*  rowminf  = (float*)((char*)d_ws + 1127424);       // 1127424 .. 1130624
  int*    rowargj  = (int*)((char*)d_ws + 1130624);         // 1130624 .. 1133824

  cost_kernel<<<Bb * NTt, 64, 0, stream>>>(category, bbox, box_preds, cat_preds,
                                           gcost, gcls, rowminf, rowargj);

  const int STAGED_LDS = NTt * NPp * 4;                     // 120000
  hipError_t e = hipFuncSetAttribute(
      reinterpret_cast<const void*>(&jv_kernel<true>),
      hipFuncAttributeMaxDynamicSharedMemorySize, STAGED_LDS);
  if (e == hipSuccess) {
    jv_kernel<true><<<Bb, 256, STAGED_LDS, stream>>>(num_objects, cat_preds,
                                                     gcost, rowminf, rowargj,
                                                     pj_g, partials);
  } else {
    jv_kernel<false><<<Bb, 256, 0, stream>>>(num_objects, cat_preds,
                                             gcost, rowminf, rowargj,
                                             pj_g, partials);
  }

  loss_kernel<<<Bb * NPp, 64, 0, stream>>>(attribute, bbox, cat_preds,
                                           attribute_preds, box_preds, gcls,
                                           pj_g, colpart);
  combine1_kernel<<<Bb * 7, 64, 0, stream>>>(colpart, partials);
  final_kernel<<<1, 64, 0, stream>>>(partials, num_objects, out);
}

// Round 15
// 102.098 us; speedup vs baseline: 1.2998x; 1.0600x over previous
//
#include <hip/hip_runtime.h>
#include <math.h>

#define Bb 8
#define NTt 100
#define NPp 300
#define Cc 92
#define Aa 64

// ---------- shared math helpers (f32, op-for-op like the reference) ----------

__device__ __forceinline__ void iou_giou_f(const float* bt, const float* bp,
                                           float& iou, float& giou) {
  float ay1 = bt[0], ax1 = bt[1], ay2 = bt[2], ax2 = bt[3];
  float by1 = bp[0], bx1 = bp[1], by2 = bp[2], bx2 = bp[3];
  float area_a = fmaxf(ay2 - ay1, 0.0f) * fmaxf(ax2 - ax1, 0.0f);
  float area_b = fmaxf(by2 - by1, 0.0f) * fmaxf(bx2 - bx1, 0.0f);
  float inter = fmaxf(fminf(ay2, by2) - fmaxf(ay1, by1), 0.0f) *
                fmaxf(fminf(ax2, bx2) - fmaxf(ax1, bx1), 0.0f);
  float un = area_a + area_b - inter;
  iou = (un > 0.0f) ? (inter / un) : 0.0f;
  float enc = fmaxf(fmaxf(ay2, by2) - fminf(ay1, by1), 0.0f) *
              fmaxf(fmaxf(ax2, bx2) - fminf(ax1, bx1), 0.0f);
  giou = iou - ((enc > 0.0f) ? ((enc - un) / enc) : 0.0f);
}

__device__ __forceinline__ float box_cost_f(const float* bt, const float* bp,
                                            float& iou_out) {
  float iou, giou;
  iou_giou_f(bt, bp, iou, giou);
  iou_out = iou;
  float l1 = (fabsf(bt[0] - bp[0]) + fabsf(bt[1] - bp[1]) +
              fabsf(bt[2] - bp[2]) + fabsf(bt[3] - bp[3])) * 0.25f;
  return 2.0f * (1.0f - giou) + 5.0f * l1;
}

// ---------- DPP helpers ----------

template <int CTRL>
__device__ __forceinline__ void dpp_fmin64(double& val) {
  union DU { double d; int i[2]; };
  DU a; a.d = val;
  int lo = __builtin_amdgcn_update_dpp(a.i[0], a.i[0], CTRL, 0xF, 0xF, false);
  int hi = __builtin_amdgcn_update_dpp(a.i[1], a.i[1], CTRL, 0xF, 0xF, false);
  DU o; o.i[0] = lo; o.i[1] = hi;
  val = fmin(val, o.d);
}

template <int CTRL>
__device__ __forceinline__ void dpp_step4(double& a, double& b, double& c, double& d) {
  dpp_fmin64<CTRL>(a); dpp_fmin64<CTRL>(b); dpp_fmin64<CTRL>(c); dpp_fmin64<CTRL>(d);
}

template <int CTRL>
__device__ __forceinline__ void dpp_umin32(unsigned int& val) {
  unsigned int o = (unsigned int)__builtin_amdgcn_update_dpp(
      (int)val, (int)val, CTRL, 0xF, 0xF, false);
  val = (o < val) ? o : val;
}

__device__ __forceinline__ unsigned int wave_umin32_bcast(unsigned int x) {
  dpp_umin32<0x111>(x);
  dpp_umin32<0x112>(x);
  dpp_umin32<0x114>(x);
  dpp_umin32<0x118>(x);
  dpp_umin32<0x142>(x);
  dpp_umin32<0x143>(x);
  return (unsigned int)__builtin_amdgcn_readlane((int)x, 63);
}

__device__ __forceinline__ double lane63_bcast(double x) {
  union DU { double d; int i[2]; };
  DU w; w.d = x;
  DU r;
  r.i[0] = __builtin_amdgcn_readlane(w.i[0], 63);
  r.i[1] = __builtin_amdgcn_readlane(w.i[1], 63);
  return r.d;
}

__device__ __forceinline__ double wave_fmin64_bcast(double m01) {
  double mv = m01;
  dpp_fmin64<0x111>(mv);
  dpp_fmin64<0x112>(mv);
  dpp_fmin64<0x114>(mv);
  dpp_fmin64<0x118>(mv);
  dpp_fmin64<0x142>(mv);
  dpp_fmin64<0x143>(mv);
  return lane63_bcast(mv);
}

__device__ __forceinline__ double read_u_row(double u_lo, double u_hi, int i0u) {
  int ridx = i0u - 1;
  int src = ridx & 63;
  union DU { double d; int i[2]; };
  DU a, bb, r;
  a.d = u_lo; bb.d = u_hi;
  int lo0 = __builtin_amdgcn_readlane(a.i[0], src);
  int hi0 = __builtin_amdgcn_readlane(a.i[1], src);
  int lo1 = __builtin_amdgcn_readlane(bb.i[0], src);
  int hi1 = __builtin_amdgcn_readlane(bb.i[1], src);
  bool hih = (ridx >> 6) != 0;
  r.i[0] = hih ? lo1 : lo0;
  r.i[1] = hih ? hi1 : hi0;
  return r.d;
}

__device__ __forceinline__ int sel5(int s, int a0, int a1, int a2, int a3, int a4) {
  int r = a4;
  r = (s == 3) ? a3 : r;
  r = (s == 2) ? a2 : r;
  r = (s == 1) ? a1 : r;
  r = (s == 0) ? a0 : r;
  return r;
}

// ---------- K1: cls + match-cost + per-row f32 (min, argmin) (800 blocks) ----------
// cost >= 0 so f32 bits are u32-monotonic: stage-1 u32 DPP min of value bits,
// stage-2 u32 DPP min of column indices among min-holders (np.argmin tie rule).
// f32->f64 injective & monotone => equals the reference's f64 argmin at v=0.

__global__ void __launch_bounds__(64) cost_kernel(
    const float* __restrict__ category, const float* __restrict__ bbox,
    const float* __restrict__ box_preds, const float* __restrict__ cat_preds,
    float* __restrict__ cost, int* __restrict__ cls,
    float* __restrict__ rowminf, int* __restrict__ rowargj) {
  int bt = blockIdx.x;                 // 0..799
  int b = bt / NTt;
  int lane = threadIdx.x;

  const float* crow = category + (size_t)bt * Cc;
  float c0 = (lane < Cc) ? crow[lane] : 0.0f;
  float c1 = (lane < Cc - 64) ? crow[lane + 64] : 0.0f;
  unsigned long long m0 = __ballot(c0 == 1.0f);
  unsigned long long m1 = __ballot(c1 == 1.0f);
  int cl = m0 ? __builtin_ctzll(m0) : (m1 ? 64 + __builtin_ctzll(m1) : 0);
  if (lane == 0) cls[bt] = cl;

  float tb[4];
  tb[0] = bbox[(size_t)bt * 4 + 0];
  tb[1] = bbox[(size_t)bt * 4 + 1];
  tb[2] = bbox[(size_t)bt * 4 + 2];
  tb[3] = bbox[(size_t)bt * 4 + 3];

  const float4* bp4 = (const float4*)(box_preds + (size_t)b * NPp * 4);
  const float* cp = cat_preds + (size_t)b * NPp * Cc + cl;
  float* crow_out = cost + (size_t)bt * NPp;

  float lmin = __builtin_inff();
  int   larg = 0x7FFFFFFF;

  #pragma unroll
  for (int k = 0; k < 5; ++k) {
    int p = lane + (k << 6);
    if (p < NPp) {
      float4 bpv = bp4[p];
      float pb[4] = {bpv.x, bpv.y, bpv.z, bpv.w};
      float iou;
      float bc = box_cost_f(tb, pb, iou);
      float pc = cp[(size_t)p * Cc];
      float cv = (1.0f - pc) + bc;
      crow_out[p] = cv;
      if (cv < lmin) { lmin = cv; larg = p; }   // ascending p => first-min
    }
  }

  union FU { float f; unsigned int u; };
  FU fu; fu.f = lmin;
  unsigned int minbits = wave_umin32_bcast(fu.u);
  unsigned int cand = (fu.u == minbits) ? (unsigned int)larg : 0xFFFFFFFFu;
  unsigned int argj = wave_umin32_bcast(cand);

  if (lane == 0) {
    FU mb; mb.u = minbits;
    rowminf[bt] = mb.f;
    rowargj[bt] = (int)argj;
  }
}

// ---------- K2: LDS-staged JV: phase-A precomputed claims, batch-4 fast path,
// and fallback with ITERATION-1 SHORTCUT (8 blocks x 256) ----------
// Shortcut exactness: at a row's first Dijkstra iteration u[i]=0, used={}, so
// minv[j] = (double)c[i][j] - v[j] == the batch key bitwise ((c-0)-v == c-v);
// its side effects are way[j]=0 for all j, minv -= delta, u[i] += delta, and
// settling the argmin column (v untouched: used = {virtual col 0}). We seed
// that state from the batch's (delta, j1) and enter the loop at iteration 2.
// Column map: lane L (<60) owns j = 5L+1..5L+5.

template <bool STAGE>
__global__ void __launch_bounds__(256, 1) jv_kernel(
    const int* __restrict__ num_objects, const float* __restrict__ cat_preds,
    const float* __restrict__ gcost, const float* __restrict__ rowminf,
    const int* __restrict__ rowargj, int* __restrict__ pj_g,
    double* __restrict__ partials) {
  extern __shared__ char smem[];
  const int b = blockIdx.x;
  const int tid = threadIdx.x;
  const int lane = tid & 63;

  float* lds_cost = (float*)smem;
  const int n = num_objects[b];
  const float* costg = gcost + (size_t)b * NTt * NPp;

  if (STAGE) {
    const float4* s4 = (const float4*)costg;
    float4* d4 = (float4*)lds_cost;
    int n4 = n * (NPp / 4);
    for (int t = tid; t < n4; t += 256) d4[t] = s4[t];
  }
  __syncthreads();

  if (tid >= 64) return;     // waves 1-3 done; wave 0 runs JV barrier-free

  const float* costb = STAGE ? lds_cost : costg;

  const double INF = __builtin_inf();
  const bool active = lane < 60;
  const int laneOff = active ? 5 * lane : 0;

  double v0 = 0.0, v1 = 0.0, v2 = 0.0, v3 = 0.0, v4 = 0.0;
  double u_lo = 0.0, u_hi = 0.0;                 // u[lane+1], u[lane+65]
  int wp0 = 0, wp1 = 0, wp2 = 0, wp3 = 0, wp4 = 0;   // (way<<7)|pj per slot
  int occm = 0;                                  // 5-bit occupancy of my cols

  // ---- phase A: precomputed claims while v == 0 ----
  float mf0 = (lane < n) ? rowminf[b * NTt + lane] : 0.0f;
  int   aj0 = (lane < n) ? rowargj[b * NTt + lane] : 0;
  float mf1 = (lane + 64 < n) ? rowminf[b * NTt + lane + 64] : 0.0f;
  int   aj1 = (lane + 64 < n) ? rowargj[b * NTt + lane + 64] : 0;

  unsigned long long M0 = 0, M1 = 0, M2 = 0, M3 = 0, M4 = 0;  // uniform masks
  int i = 1;
  while (i <= n) {
    int ridx = i - 1;
    int j1 = (ridx >> 6) ? __builtin_amdgcn_readlane(aj1, ridx & 63)
                         : __builtin_amdgcn_readlane(aj0, ridx & 63);
    int ow = j1 / 5, sk = j1 - 5 * (j1 / 5);     // j1 is 0-based column
    unsigned long long Ms = (sk == 0) ? M0 : (sk == 1) ? M1 :
                            (sk == 2) ? M2 : (sk == 3) ? M3 : M4;
    if ((Ms >> ow) & 1) break;                   // collision -> phase B
    if      (sk == 0) M0 |= 1ull << ow;
    else if (sk == 1) M1 |= 1ull << ow;
    else if (sk == 2) M2 |= 1ull << ow;
    else if (sk == 3) M3 |= 1ull << ow;
    else              M4 |= 1ull << ow;
    if (lane == ow) {
      occm |= 1 << sk;
      if      (sk == 0) wp0 = (wp0 & ~127) | i;
      else if (sk == 1) wp1 = (wp1 & ~127) | i;
      else if (sk == 2) wp2 = (wp2 & ~127) | i;
      else if (sk == 3) wp3 = (wp3 & ~127) | i;
      else              wp4 = (wp4 & ~127) | i;
    }
    if ((ridx & 63) == lane) {
      if (ridx >> 6) u_hi += (double)mf1; else u_lo += (double)mf0;
    }
    ++i;
  }

  // ---- phase B: batch-4 fast path + fallback w/ iteration-1 shortcut ----
  while (i <= n) {
    int cnt = n - i + 1; if (cnt > 4) cnt = 4;

    double m[4]; int p01a[4];
    #pragma unroll
    for (int r = 0; r < 4; ++r) {
      int row = i + r; if (row > n) row = n;     // pad (result unused)
      const float* rowp = costb + (row - 1) * NPp + laneOff;
      float ca = rowp[0], cb2 = rowp[1], cc = rowp[2], cd = rowp[3], ce = rowp[4];
      double cv0 = active ? (double)ca - v0 : INF;
      double cv1 = active ? (double)cb2 - v1 : INF;
      double cv2 = active ? (double)cc - v2 : INF;
      double cv3 = active ? (double)cd - v3 : INF;
      double cv4 = active ? (double)ce - v4 : INF;
      double m01 = fmin(fmin(fmin(cv0, cv1), fmin(cv2, cv3)), cv4);
      int k0 = (cv3 == m01) ? 3 : 4;
      k0 = (cv2 == m01) ? 2 : k0;
      k0 = (cv1 == m01) ? 1 : k0;
      k0 = (cv0 == m01) ? 0 : k0;
      m[r] = m01;
      p01a[r] = laneOff + k0 + 1;
    }
    double r0 = m[0], r1 = m[1], r2 = m[2], r3 = m[3];
    dpp_step4<0x111>(r0, r1, r2, r3);
    dpp_step4<0x112>(r0, r1, r2, r3);
    dpp_step4<0x114>(r0, r1, r2, r3);
    dpp_step4<0x118>(r0, r1, r2, r3);
    dpp_step4<0x142>(r0, r1, r2, r3);
    dpp_step4<0x143>(r0, r1, r2, r3);
    double dly[4]; int jw[4];
    {
      double rr[4] = {r0, r1, r2, r3};
      #pragma unroll
      for (int r = 0; r < 4; ++r) {
        double delta = lane63_bcast(rr[r]);
        unsigned long long hit = __ballot(m[r] == delta);
        int winlane = __builtin_ctzll(hit);
        dly[r] = delta;
        jw[r] = __builtin_amdgcn_readlane(p01a[r], winlane);
      }
    }

    int consumed = 0, fbrow = 0;
    double fb_delta = 0.0; int fb_j1 = 0;        // saved at compile-time index
    #pragma unroll
    for (int r = 0; r < 4; ++r) {
      if (r < cnt && fbrow == 0) {
        int row = i + r;
        int j1 = jw[r];
        int jm = j1 - 1, ow = jm / 5, sk = jm - 5 * (jm / 5);
        unsigned long long mset = __ballot((occm >> sk) & 1);
        bool occ = (mset >> ow) & 1;
        consumed = r + 1;                        // includes collided row
        if (!occ) {
          if (lane == ow) {
            occm |= 1 << sk;
            if      (sk == 0) wp0 = (wp0 & ~127) | row;
            else if (sk == 1) wp1 = (wp1 & ~127) | row;
            else if (sk == 2) wp2 = (wp2 & ~127) | row;
            else if (sk == 3) wp3 = (wp3 & ~127) | row;
            else              wp4 = (wp4 & ~127) | row;
          }
          int ridx = row - 1;
          if ((ridx & 63) == lane) {
            if (ridx >> 6) u_hi += dly[r]; else u_lo += dly[r];
          }
        } else {
          fbrow = row; fb_delta = dly[r]; fb_j1 = j1;
        }
      }
    }

    if (fbrow) {
      // ---- iteration-1 shortcut: seed state from (fb_delta, fb_j1) ----
      const double delta1 = fb_delta;
      const float* rowp1 = costb + (fbrow - 1) * NPp + laneOff;
      float fa1 = rowp1[0], fb1 = rowp1[1], fc1 = rowp1[2],
            fd1 = rowp1[3], fe1 = rowp1[4];
      double mv0 = (double)fa1 - v0;   // == (c - u[i]=0) - v bitwise
      double mv1 = (double)fb1 - v1;
      double mv2 = (double)fc1 - v2;
      double mv3 = (double)fd1 - v3;
      double mv4 = (double)fe1 - v4;
      wp0 &= 127; wp1 &= 127; wp2 &= 127; wp3 &= 127; wp4 &= 127;  // way=0
      int usedmask = 0, uf = 0;
      {
        int ridx = fbrow - 1;
        if ((ridx & 63) == lane) {
          uf = 1 << (ridx >> 6);
          if (ridx >> 6) u_hi += delta1; else u_lo += delta1;
        }
      }
      mv0 -= delta1; mv1 -= delta1; mv2 -= delta1; mv3 -= delta1; mv4 -= delta1;

      int jm0 = fb_j1 - 1, wl0 = jm0 / 5, sk0 = jm0 - 5 * wl0;
      if (lane == wl0) {
        usedmask = 1 << sk0;
        if      (sk0 == 0) mv0 = -INF;
        else if (sk0 == 1) mv1 = -INF;
        else if (sk0 == 2) mv2 = -INF;
        else if (sk0 == 3) mv3 = -INF;
        else               mv4 = -INF;
      }
      int o0 = __builtin_amdgcn_readlane(wp0, wl0),
          o1 = __builtin_amdgcn_readlane(wp1, wl0),
          o2 = __builtin_amdgcn_readlane(wp2, wl0),
          o3 = __builtin_amdgcn_readlane(wp3, wl0),
          o4 = __builtin_amdgcn_readlane(wp4, wl0);
      int i0u = sel5(sk0, o0 & 127, o1 & 127, o2 & 127, o3 & 127, o4 & 127);
      int j0u = fb_j1;

      // ---- iterations 2..: unchanged bit-exact Dijkstra ----
      while (true) {
        { int ridx = i0u - 1; if ((ridx & 63) == lane) uf |= 1 << (ridx >> 6); }

        const float* rowp = costb + (i0u - 1) * NPp + laneOff;
        float fa = rowp[0], fb = rowp[1], fc = rowp[2], fd = rowp[3], fe = rowp[4];
        double ui0 = read_u_row(u_lo, u_hi, i0u);

        {
          double cur = (double)fa - ui0 - v0;
          wp0 = (cur < mv0) ? ((j0u << 7) | (wp0 & 127)) : wp0;
          mv0 = fmin(mv0, cur);
        }
        {
          double cur = (double)fb - ui0 - v1;
          wp1 = (cur < mv1) ? ((j0u << 7) | (wp1 & 127)) : wp1;
          mv1 = fmin(mv1, cur);
        }
        {
          double cur = (double)fc - ui0 - v2;
          wp2 = (cur < mv2) ? ((j0u << 7) | (wp2 & 127)) : wp2;
          mv2 = fmin(mv2, cur);
        }
        {
          double cur = (double)fd - ui0 - v3;
          wp3 = (cur < mv3) ? ((j0u << 7) | (wp3 & 127)) : wp3;
          mv3 = fmin(mv3, cur);
        }
        {
          double cur = (double)fe - ui0 - v4;
          wp4 = (cur < mv4) ? ((j0u << 7) | (wp4 & 127)) : wp4;
          mv4 = fmin(mv4, cur);
        }

        double dv0 = (!active || (usedmask & 1))  ? INF : mv0;
        double dv1 = (!active || (usedmask & 2))  ? INF : mv1;
        double dv2 = (!active || (usedmask & 4))  ? INF : mv2;
        double dv3 = (!active || (usedmask & 8))  ? INF : mv3;
        double dv4 = (!active || (usedmask & 16)) ? INF : mv4;

        double mm = fmin(fmin(fmin(dv0, dv1), fmin(dv2, dv3)), dv4);
        int kk = (dv3 == mm) ? 3 : 4;
        kk = (dv2 == mm) ? 2 : kk;
        kk = (dv1 == mm) ? 1 : kk;
        kk = (dv0 == mm) ? 0 : kk;
        int pl2 = sel5(kk, wp0 & 127, wp1 & 127, wp2 & 127, wp3 & 127, wp4 & 127);
        int pk2 = ((laneOff + kk + 1) << 7) | pl2;

        double delta2 = wave_fmin64_bcast(mm);
        unsigned long long hit2 = __ballot(mm == delta2);
        int winlane2 = __builtin_ctzll(hit2);
        int wpk2 = __builtin_amdgcn_readlane(pk2, winlane2);
        int j1b = wpk2 >> 7, i1b = wpk2 & 127;

        if (uf & 1) u_lo += delta2;
        if (uf & 2) u_hi += delta2;
        v0 -= (usedmask & 1)  ? delta2 : 0.0;
        v1 -= (usedmask & 2)  ? delta2 : 0.0;
        v2 -= (usedmask & 4)  ? delta2 : 0.0;
        v3 -= (usedmask & 8)  ? delta2 : 0.0;
        v4 -= (usedmask & 16) ? delta2 : 0.0;
        mv0 -= delta2; mv1 -= delta2; mv2 -= delta2; mv3 -= delta2; mv4 -= delta2;

        int jm = j1b - 1;
        int wl = jm / 5;
        int sk = jm - 5 * wl;
        if (lane == wl) {
          usedmask |= 1 << sk;
          if      (sk == 0) mv0 = -INF;
          else if (sk == 1) mv1 = -INF;
          else if (sk == 2) mv2 = -INF;
          else if (sk == 3) mv3 = -INF;
          else              mv4 = -INF;
        }

        j0u = j1b; i0u = i1b;
        if (i0u == 0) break;
      }

      // augment alternating path (uniform readlane walk)
      {
        int jj = j0u;
        int idx = jj - 1;
        int owner = idx / 5;
        int slot = idx - 5 * owner;
        int f0 = __builtin_amdgcn_readlane(wp0, owner),
            f1 = __builtin_amdgcn_readlane(wp1, owner),
            f2 = __builtin_amdgcn_readlane(wp2, owner),
            f3 = __builtin_amdgcn_readlane(wp3, owner),
            f4 = __builtin_amdgcn_readlane(wp4, owner);
        int wpv = sel5(slot, f0, f1, f2, f3, f4);
        int wayv = wpv >> 7;

        while (true) {
          int jp = wayv;                        // uniform
          int newv;
          int wayn = 0;
          if (jp != 0) {
            int idx2 = jp - 1;
            int owner2 = idx2 / 5;
            int slot2 = idx2 - 5 * owner2;
            int g0 = __builtin_amdgcn_readlane(wp0, owner2),
                g1 = __builtin_amdgcn_readlane(wp1, owner2),
                g2 = __builtin_amdgcn_readlane(wp2, owner2),
                g3 = __builtin_amdgcn_readlane(wp3, owner2),
                g4 = __builtin_amdgcn_readlane(wp4, owner2);
            int wpn = sel5(slot2, g0, g1, g2, g3, g4);
            wayn = wpn >> 7;
            newv = wpn & 127;                   // old pj[jp]
          } else {
            newv = fbrow;
          }
          if (lane == owner) {
            if      (slot == 0) wp0 = (wp0 & ~127) | newv;
            else if (slot == 1) wp1 = (wp1 & ~127) | newv;
            else if (slot == 2) wp2 = (wp2 & ~127) | newv;
            else if (slot == 3) wp3 = (wp3 & ~127) | newv;
            else                wp4 = (wp4 & ~127) | newv;
          }
          if (jp == 0) break;
          jj = jp;
          idx = jj - 1;
          owner = idx / 5;
          slot = idx - 5 * owner;
          wayv = wayn;
        }
      }

      // refresh per-lane occupancy from wp
      occm = ((wp0 & 127) ? 1 : 0) | ((wp1 & 127) ? 2 : 0) |
             ((wp2 & 127) ? 4 : 0) | ((wp3 & 127) ? 8 : 0) |
             ((wp4 & 127) ? 16 : 0);
    }

    i += consumed;
  }

  // export assignment
  if (active) {
    int base = b * 304;
    pj_g[base + 5 * lane + 1] = wp0 & 127;
    pj_g[base + 5 * lane + 2] = wp1 & 127;
    pj_g[base + 5 * lane + 3] = wp2 & 127;
    pj_g[base + 5 * lane + 4] = wp3 & 127;
    pj_g[base + 5 * lane + 5] = wp4 & 127;
  }

  // num_predicted contribution: count cat_preds[b,1,:] < 0.5
  const float* cpb1 = cat_preds + ((size_t)b * NPp + 1) * Cc;
  float q0 = (lane < Cc) ? cpb1[lane] : 1.0f;
  float q1 = (lane + 64 < Cc) ? cpb1[lane + 64] : 1.0f;
  unsigned long long mm0 = __ballot(q0 < 0.5f);
  unsigned long long mm1 = __ballot(q1 < 0.5f);
  if (lane == 0) partials[b * 8 + 7] = (double)(__popcll(mm0) + __popcll(mm1));
}

// ---------- K3: per-column losses, one wave per (b,j) (2400 blocks) ----------

__global__ void __launch_bounds__(64) loss_kernel(
    const float* __restrict__ attribute, const float* __restrict__ bbox,
    const float* __restrict__ cat_preds, const float* __restrict__ attribute_preds,
    const float* __restrict__ box_preds, const int* __restrict__ gcls,
    const int* __restrict__ pj_g, double* __restrict__ colpart) {
  int gb = blockIdx.x;                 // b*NPp + j
  int b = gb / NPp;
  int j = gb - b * NPp;
  int lane = threadIdx.x;
  double* outp = colpart + (size_t)gb * 8;

  int prow = pj_g[b * 304 + j + 1];
  if (prow == 0) {
    if (lane < 8) outp[lane] = 0.0;
    return;
  }

  int t = prow - 1;
  int bt = b * NTt + t;

  const float EPSF = 1e-7f;
  const float HIF  = (float)(1.0 - 1e-7);

  float y = attribute[(size_t)bt * Aa + lane];
  float p = fminf(fmaxf(attribute_preds[(size_t)gb * Aa + lane], EPSF), HIF);
  float ce = -(y * logf(p) + (1.0f - y) * logf(1.0f - p));
  float pt = y * p + (1.0f - y) * (1.0f - p);
  float alpha = y * 0.25f + (1.0f - y) * 0.75f;
  float om = 1.0f - pt;
  double sattr = (double)(alpha * (om * om) * ce);
  #pragma unroll
  for (int off = 32; off >= 1; off >>= 1) sattr += __shfl_xor(sattr, off);

  if (lane == 0) {
    int cl = gcls[bt];
    float pc = cat_preds[(size_t)gb * Cc + cl];
    double scat = (double)(-logf(pc + 1e-5f));

    const float* btp = bbox + (size_t)bt * 4;
    const float* bpp = box_preds + (size_t)gb * 4;
    float iou;
    float bc = box_cost_f(btp, bpp, iou);
    float ia = 1.0f - iou;

    double c50 = (ia >= 0.5f) ? 1.0 : 0.0;
    double call = 0.0;
    for (int rr = 50; rr < 100; rr += 5) {
      float thr = (float)((double)rr / 100.0);
      if (ia >= thr) call += 1.0;
    }

    float yp = 1.0f - cat_preds[(size_t)gb * Cc + 0];
    float pn = yp / yp;
    pn = fminf(fmaxf(pn, EPSF), HIF);
    double sex = (double)(-logf(pn));

    outp[0] = scat;
    outp[1] = sattr;
    outp[2] = (double)bc;
    outp[3] = (double)ia;
    outp[4] = sex;
    outp[5] = c50;
    outp[6] = call;
    outp[7] = 0.0;
  }
}

// ---------- K4: fixed-tree per-(b,q) sums (56 blocks x 64) ----------

__global__ void __launch_bounds__(64) combine1_kernel(
    const double* __restrict__ colpart, double* __restrict__ partials) {
  int bid = blockIdx.x;                // 0..55
  int b = bid / 7;
  int q = bid - b * 7;
  int lane = threadIdx.x;

  double s = 0.0;
  #pragma unroll
  for (int k = 0; k < 5; ++k) {
    int j = lane + (k << 6);
    if (j < NPp) s += colpart[((size_t)(b * NPp + j)) * 8 + q];
  }
  #pragma unroll
  for (int off = 32; off >= 1; off >>= 1) s += __shfl_xor(s, off);
  if (lane == 0) partials[b * 8 + q] = s;
}

// ---------- K5: final outputs ----------

__global__ void final_kernel(const double* __restrict__ partials,
                             const int* __restrict__ num_objects,
                             float* __restrict__ out) {
  if (threadIdx.x != 0) return;
  double t[8];
  #pragma unroll
  for (int q = 0; q < 8; ++q) t[q] = 0.0;
  for (int b = 0; b < Bb; ++b)
    for (int q = 0; q < 8; ++q) t[q] += partials[b * 8 + q];

  int s = 0;
  for (int b = 0; b < Bb; ++b) s += num_objects[b];
  float tno = (float)s;

  float category_cost  = (float)t[0] / tno;
  float attribute_cost = (float)t[1] / tno;
  float box_cost       = (float)t[2] / tno;
  float exist_loss     = (float)t[4] / (float)(Bb * NPp);
  float total = category_cost + attribute_cost + box_cost + exist_loss;
  float iou_metric = (float)t[3] / tno;
  float npredf = (float)t[7];
  float mAP50 = (float)t[5] / npredf;
  float m5095 = (float)t[6] / (npredf * 10.0f);

  out[0] = total;
  out[1] = category_cost;
  out[2] = attribute_cost;
  out[3] = box_cost;
  out[4] = exist_loss;
  out[5] = iou_metric;
  out[6] = mAP50;
  out[7] = m5095;
}

// ---------- launcher ----------

extern "C" void kernel_launch(void* const* d_in, const int* in_sizes, int n_in,
                              void* d_out, int out_size, void* d_ws, size_t ws_size,
                              hipStream_t stream) {
  const float* category        = (const float*)d_in[0];
  const float* attribute       = (const float*)d_in[1];
  const float* bbox            = (const float*)d_in[2];
  const int*   num_objects     = (const int*)d_in[3];
  const float* cat_preds       = (const float*)d_in[4];
  const float* attribute_preds = (const float*)d_in[5];
  const float* box_preds       = (const float*)d_in[6];
  float* out = (float*)d_out;

  // ws layout
  double* partials = (double*)d_ws;                         //       0 ..     512
  int*    gcls     = (int*)((char*)d_ws + 512);             //     512 ..    3712
  float*  gcost    = (float*)((char*)d_ws + 4096);          //    4096 ..  964096
  int*    pj_g     = (int*)((char*)d_ws + 964096);          //  964096 ..  973824
  double* colpart  = (double*)((char*)d_ws + 973824);       //  973824 .. 1127424
  float*  rowminf  = (float*)((char*)d_ws + 1127424);       // 1127424 .. 1130624
  int*    rowargj  = (int*)((char*)d_ws + 1130624);         // 1130624 .. 1133824

  cost_kernel<<<Bb * NTt, 64, 0, stream>>>(category, bbox, box_preds, cat_preds,
                                           gcost, gcls, rowminf, rowargj);

  const int STAGED_LDS = NTt * NPp * 4;                     // 120000
  hipError_t e = hipFuncSetAttribute(
      reinterpret_cast<const void*>(&jv_kernel<true>),
      hipFuncAttributeMaxDynamicSharedMemorySize, STAGED_LDS);
  if (e == hipSuccess) {
    jv_kernel<true><<<Bb, 256, STAGED_LDS, stream>>>(num_objects, cat_preds,
                                                     gcost, rowminf, rowargj,
                                                     pj_g, partials);
  } else {
    jv_kernel<false><<<Bb, 256, 0, stream>>>(num_objects, cat_preds,
                                             gcost, rowminf, rowargj,
                                             pj_g, partials);
  }

  loss_kernel<<<Bb * NPp, 64, 0, stream>>>(attribute, bbox, cat_preds,
                                           attribute_preds, box_preds, gcls,
                                           pj_g, colpart);
  combine1_kernel<<<Bb * 7, 64, 0, stream>>>(colpart, partials);
  final_kernel<<<1, 64, 0, stream>>>(partials, num_objects, out);
}

// Round 16
// 100.764 us; speedup vs baseline: 1.3171x; 1.0132x over previous
//
#include <hip/hip_runtime.h>
#include <math.h>

#define Bb 8
#define NTt 100
#define NPp 300
#define Cc 92
#define Aa 64

// ---------- shared math helpers (f32, op-for-op like the reference) ----------

__device__ __forceinline__ void iou_giou_f(const float* bt, const float* bp,
                                           float& iou, float& giou) {
  float ay1 = bt[0], ax1 = bt[1], ay2 = bt[2], ax2 = bt[3];
  float by1 = bp[0], bx1 = bp[1], by2 = bp[2], bx2 = bp[3];
  float area_a = fmaxf(ay2 - ay1, 0.0f) * fmaxf(ax2 - ax1, 0.0f);
  float area_b = fmaxf(by2 - by1, 0.0f) * fmaxf(bx2 - bx1, 0.0f);
  float inter = fmaxf(fminf(ay2, by2) - fmaxf(ay1, by1), 0.0f) *
                fmaxf(fminf(ax2, bx2) - fmaxf(ax1, bx1), 0.0f);
  float un = area_a + area_b - inter;
  iou = (un > 0.0f) ? (inter / un) : 0.0f;
  float enc = fmaxf(fmaxf(ay2, by2) - fminf(ay1, by1), 0.0f) *
              fmaxf(fmaxf(ax2, bx2) - fminf(ax1, bx1), 0.0f);
  giou = iou - ((enc > 0.0f) ? ((enc - un) / enc) : 0.0f);
}

__device__ __forceinline__ float box_cost_f(const float* bt, const float* bp,
                                            float& iou_out) {
  float iou, giou;
  iou_giou_f(bt, bp, iou, giou);
  iou_out = iou;
  float l1 = (fabsf(bt[0] - bp[0]) + fabsf(bt[1] - bp[1]) +
              fabsf(bt[2] - bp[2]) + fabsf(bt[3] - bp[3])) * 0.25f;
  return 2.0f * (1.0f - giou) + 5.0f * l1;
}

// ---------- DPP helpers ----------

template <int CTRL>
__device__ __forceinline__ void dpp_fmin64(double& val) {
  union DU { double d; int i[2]; };
  DU a; a.d = val;
  int lo = __builtin_amdgcn_update_dpp(a.i[0], a.i[0], CTRL, 0xF, 0xF, false);
  int hi = __builtin_amdgcn_update_dpp(a.i[1], a.i[1], CTRL, 0xF, 0xF, false);
  DU o; o.i[0] = lo; o.i[1] = hi;
  val = fmin(val, o.d);
}

template <int CTRL>
__device__ __forceinline__ void dpp_umin32(unsigned int& val) {
  unsigned int o = (unsigned int)__builtin_amdgcn_update_dpp(
      (int)val, (int)val, CTRL, 0xF, 0xF, false);
  val = (o < val) ? o : val;
}

__device__ __forceinline__ unsigned int wave_umin32_bcast(unsigned int x) {
  dpp_umin32<0x111>(x);
  dpp_umin32<0x112>(x);
  dpp_umin32<0x114>(x);
  dpp_umin32<0x118>(x);
  dpp_umin32<0x142>(x);
  dpp_umin32<0x143>(x);
  return (unsigned int)__builtin_amdgcn_readlane((int)x, 63);
}

__device__ __forceinline__ double lane63_bcast(double x) {
  union DU { double d; int i[2]; };
  DU w; w.d = x;
  DU r;
  r.i[0] = __builtin_amdgcn_readlane(w.i[0], 63);
  r.i[1] = __builtin_amdgcn_readlane(w.i[1], 63);
  return r.d;
}

__device__ __forceinline__ double wave_fmin64_bcast(double m01) {
  double mv = m01;
  dpp_fmin64<0x111>(mv);
  dpp_fmin64<0x112>(mv);
  dpp_fmin64<0x114>(mv);
  dpp_fmin64<0x118>(mv);
  dpp_fmin64<0x142>(mv);
  dpp_fmin64<0x143>(mv);
  return lane63_bcast(mv);
}

__device__ __forceinline__ double read_u_row(double u_lo, double u_hi, int i0u) {
  int ridx = i0u - 1;
  int src = ridx & 63;
  union DU { double d; int i[2]; };
  DU a, bb, r;
  a.d = u_lo; bb.d = u_hi;
  int lo0 = __builtin_amdgcn_readlane(a.i[0], src);
  int hi0 = __builtin_amdgcn_readlane(a.i[1], src);
  int lo1 = __builtin_amdgcn_readlane(bb.i[0], src);
  int hi1 = __builtin_amdgcn_readlane(bb.i[1], src);
  bool hih = (ridx >> 6) != 0;
  r.i[0] = hih ? lo1 : lo0;
  r.i[1] = hih ? hi1 : hi0;
  return r.d;
}

__device__ __forceinline__ int sel5(int s, int a0, int a1, int a2, int a3, int a4) {
  int r = a4;
  r = (s == 3) ? a3 : r;
  r = (s == 2) ? a2 : r;
  r = (s == 1) ? a1 : r;
  r = (s == 0) ? a0 : r;
  return r;
}

__device__ __forceinline__ unsigned long long selm5(int s,
    unsigned long long a0, unsigned long long a1, unsigned long long a2,
    unsigned long long a3, unsigned long long a4) {
  unsigned long long r = a4;
  r = (s == 3) ? a3 : r;
  r = (s == 2) ? a2 : r;
  r = (s == 1) ? a1 : r;
  r = (s == 0) ? a0 : r;
  return r;
}

// ---------- K1: cls + match-cost + per-row f32 (min, argmin) (800 blocks) ----------
// cost >= 0 so f32 bits are u32-monotonic: stage-1 u32 DPP min of value bits,
// stage-2 u32 DPP min of column indices among min-holders (np.argmin tie rule).

__global__ void __launch_bounds__(64) cost_kernel(
    const float* __restrict__ category, const float* __restrict__ bbox,
    const float* __restrict__ box_preds, const float* __restrict__ cat_preds,
    float* __restrict__ cost, int* __restrict__ cls,
    float* __restrict__ rowminf, int* __restrict__ rowargj) {
  int bt = blockIdx.x;                 // 0..799
  int b = bt / NTt;
  int lane = threadIdx.x;

  const float* crow = category + (size_t)bt * Cc;
  float c0 = (lane < Cc) ? crow[lane] : 0.0f;
  float c1 = (lane < Cc - 64) ? crow[lane + 64] : 0.0f;
  unsigned long long m0 = __ballot(c0 == 1.0f);
  unsigned long long m1 = __ballot(c1 == 1.0f);
  int cl = m0 ? __builtin_ctzll(m0) : (m1 ? 64 + __builtin_ctzll(m1) : 0);
  if (lane == 0) cls[bt] = cl;

  float tb[4];
  tb[0] = bbox[(size_t)bt * 4 + 0];
  tb[1] = bbox[(size_t)bt * 4 + 1];
  tb[2] = bbox[(size_t)bt * 4 + 2];
  tb[3] = bbox[(size_t)bt * 4 + 3];

  const float4* bp4 = (const float4*)(box_preds + (size_t)b * NPp * 4);
  const float* cp = cat_preds + (size_t)b * NPp * Cc + cl;
  float* crow_out = cost + (size_t)bt * NPp;

  float lmin = __builtin_inff();
  int   larg = 0x7FFFFFFF;

  #pragma unroll
  for (int k = 0; k < 5; ++k) {
    int p = lane + (k << 6);
    if (p < NPp) {
      float4 bpv = bp4[p];
      float pb[4] = {bpv.x, bpv.y, bpv.z, bpv.w};
      float iou;
      float bc = box_cost_f(tb, pb, iou);
      float pc = cp[(size_t)p * Cc];
      float cv = (1.0f - pc) + bc;
      crow_out[p] = cv;
      if (cv < lmin) { lmin = cv; larg = p; }   // ascending p => first-min
    }
  }

  union FU { float f; unsigned int u; };
  FU fu; fu.f = lmin;
  unsigned int minbits = wave_umin32_bcast(fu.u);
  unsigned int cand = (fu.u == minbits) ? (unsigned int)larg : 0xFFFFFFFFu;
  unsigned int argj = wave_umin32_bcast(cand);

  if (lane == 0) {
    FU mb; mb.u = minbits;
    rowminf[bt] = mb.f;
    rowargj[bt] = (int)argj;
  }
}

// ---------- K2: LDS-staged JV with S-mask unified fast loop (8 blocks x 256) ----------
// S = columns whose dual v was EVER modified (union of fallback used-sets; a
// safe over-approximation). EXACT claim-preservation theorem: JV deltas >= 0
// => v <= 0 => all keys c_j - v_j >= c_j, while key_{j*} (j* not in S) is
// unchanged; the precomputed first-min at j* had c_j > c_{j*} strictly for
// j < j*, so the current iteration-1 argmin AND min value are bit-identical
// to the precomputed (rowargj, rowminf). Rows need the full key recompute
// ONLY when j* in S. Fallback = R15's iteration-1 shortcut + bit-exact
// Dijkstra. Column map: lane L (<60) owns j = 5L+1..5L+5.

template <bool STAGE>
__global__ void __launch_bounds__(256, 1) jv_kernel(
    const int* __restrict__ num_objects, const float* __restrict__ cat_preds,
    const float* __restrict__ gcost, const float* __restrict__ rowminf,
    const int* __restrict__ rowargj, int* __restrict__ pj_g,
    double* __restrict__ partials) {
  extern __shared__ char smem[];
  const int b = blockIdx.x;
  const int tid = threadIdx.x;
  const int lane = tid & 63;

  float* lds_cost = (float*)smem;
  const int n = num_objects[b];
  const float* costg = gcost + (size_t)b * NTt * NPp;

  if (STAGE) {
    const float4* s4 = (const float4*)costg;
    float4* d4 = (float4*)lds_cost;
    int n4 = n * (NPp / 4);
    for (int t = tid; t < n4; t += 256) d4[t] = s4[t];
  }
  __syncthreads();

  if (tid >= 64) return;     // waves 1-3 done; wave 0 runs JV barrier-free

  const float* costb = STAGE ? lds_cost : costg;

  const double INF = __builtin_inf();
  const bool active = lane < 60;
  const int laneOff = active ? 5 * lane : 0;

  double v0 = 0.0, v1 = 0.0, v2 = 0.0, v3 = 0.0, v4 = 0.0;
  double u_lo = 0.0, u_hi = 0.0;                 // u[lane+1], u[lane+65]
  int wp0 = 0, wp1 = 0, wp2 = 0, wp3 = 0, wp4 = 0;   // (way<<7)|pj per slot
  int occm = 0;                                  // 5-bit occupancy of my cols
  unsigned long long M0 = 0, M1 = 0, M2 = 0, M3 = 0, M4 = 0;  // occupancy
  unsigned long long S0 = 0, S1 = 0, S2 = 0, S3 = 0, S4 = 0;  // v-modified

  // per-row precomputed (min,argmin): lane (r-1)&63 holds row r's data
  float mf0 = (lane < n) ? rowminf[b * NTt + lane] : 0.0f;
  int   aj0 = (lane < n) ? rowargj[b * NTt + lane] : 0;
  float mf1 = (lane + 64 < n) ? rowminf[b * NTt + lane + 64] : 0.0f;
  int   aj1 = (lane + 64 < n) ? rowargj[b * NTt + lane + 64] : 0;

  int i = 1;
  while (i <= n) {
    int ridx = i - 1;
    int src = ridx & 63;
    bool hi = (ridx >> 6) != 0;

    bool needfb = false;
    double fb_delta = 0.0;
    int fb_j1 = 0;                               // 1-based

    int j1z = hi ? __builtin_amdgcn_readlane(aj1, src)
                 : __builtin_amdgcn_readlane(aj0, src);      // 0-based col
    int ow = j1z / 5, sk = j1z - 5 * (j1z / 5);
    unsigned long long Sms = selm5(sk, S0, S1, S2, S3, S4);

    if (!((Sms >> ow) & 1)) {
      // precomputed argmin still exact (theorem above)
      unsigned long long Ms = selm5(sk, M0, M1, M2, M3, M4);
      if (!((Ms >> ow) & 1)) {
        // SALU claim: assign + u[i] += (double)rowminf
        if      (sk == 0) M0 |= 1ull << ow;
        else if (sk == 1) M1 |= 1ull << ow;
        else if (sk == 2) M2 |= 1ull << ow;
        else if (sk == 3) M3 |= 1ull << ow;
        else              M4 |= 1ull << ow;
        if (lane == ow) {
          occm |= 1 << sk;
          if      (sk == 0) wp0 = (wp0 & ~127) | i;
          else if (sk == 1) wp1 = (wp1 & ~127) | i;
          else if (sk == 2) wp2 = (wp2 & ~127) | i;
          else if (sk == 3) wp3 = (wp3 & ~127) | i;
          else              wp4 = (wp4 & ~127) | i;
        }
        if (src == lane) {
          if (hi) u_hi += (double)mf1; else u_lo += (double)mf0;
        }
        ++i;
        continue;
      }
      // occupied -> fallback with delta = (double)rowminf[i] (bit-exact)
      int fbbits = hi ? __builtin_amdgcn_readlane(__float_as_int(mf1), src)
                      : __builtin_amdgcn_readlane(__float_as_int(mf0), src);
      fb_delta = (double)__int_as_float(fbbits);
      fb_j1 = j1z + 1;
      needfb = true;
    } else {
      // j* in S: recompute row i's iteration-1 keys with current v
      const float* rowp = costb + ridx * NPp + laneOff;
      float ca = rowp[0], cb2 = rowp[1], cc = rowp[2], cd = rowp[3], ce = rowp[4];
      double cv0 = active ? (double)ca - v0 : INF;
      double cv1 = active ? (double)cb2 - v1 : INF;
      double cv2 = active ? (double)cc - v2 : INF;
      double cv3 = active ? (double)cd - v3 : INF;
      double cv4 = active ? (double)ce - v4 : INF;
      double m01 = fmin(fmin(fmin(cv0, cv1), fmin(cv2, cv3)), cv4);
      int k0 = (cv3 == m01) ? 3 : 4;
      k0 = (cv2 == m01) ? 2 : k0;
      k0 = (cv1 == m01) ? 1 : k0;
      k0 = (cv0 == m01) ? 0 : k0;
      int p01 = laneOff + k0 + 1;
      double delta = wave_fmin64_bcast(m01);
      unsigned long long hit = __ballot(m01 == delta);
      int winlane = __builtin_ctzll(hit);
      int j1b = __builtin_amdgcn_readlane(p01, winlane);     // 1-based
      int jm = j1b - 1, ow2 = jm / 5, sk2 = jm - 5 * (jm / 5);
      unsigned long long Ms2 = selm5(sk2, M0, M1, M2, M3, M4);
      if (!((Ms2 >> ow2) & 1)) {
        if      (sk2 == 0) M0 |= 1ull << ow2;
        else if (sk2 == 1) M1 |= 1ull << ow2;
        else if (sk2 == 2) M2 |= 1ull << ow2;
        else if (sk2 == 3) M3 |= 1ull << ow2;
        else              M4 |= 1ull << ow2;
        if (lane == ow2) {
          occm |= 1 << sk2;
          if      (sk2 == 0) wp0 = (wp0 & ~127) | i;
          else if (sk2 == 1) wp1 = (wp1 & ~127) | i;
          else if (sk2 == 2) wp2 = (wp2 & ~127) | i;
          else if (sk2 == 3) wp3 = (wp3 & ~127) | i;
          else               wp4 = (wp4 & ~127) | i;
        }
        if (src == lane) {
          if (hi) u_hi += delta; else u_lo += delta;
        }
        ++i;
        continue;
      }
      fb_delta = delta;
      fb_j1 = j1b;
      needfb = true;
    }

    // ---- fallback: iteration-1 shortcut + bit-exact Dijkstra ----
    int usedmask = 0;
    {
      const int fbrow = i;
      const double delta1 = fb_delta;
      const float* rowp1 = costb + (fbrow - 1) * NPp + laneOff;
      float fa1 = rowp1[0], fb1 = rowp1[1], fc1 = rowp1[2],
            fd1 = rowp1[3], fe1 = rowp1[4];
      double mv0 = (double)fa1 - v0;   // == (c - u[i]=0) - v bitwise
      double mv1 = (double)fb1 - v1;
      double mv2 = (double)fc1 - v2;
      double mv3 = (double)fd1 - v3;
      double mv4 = (double)fe1 - v4;
      wp0 &= 127; wp1 &= 127; wp2 &= 127; wp3 &= 127; wp4 &= 127;  // way=0
      int uf = 0;
      {
        int rr2 = fbrow - 1;
        if ((rr2 & 63) == lane) {
          uf = 1 << (rr2 >> 6);
          if (rr2 >> 6) u_hi += delta1; else u_lo += delta1;
        }
      }
      mv0 -= delta1; mv1 -= delta1; mv2 -= delta1; mv3 -= delta1; mv4 -= delta1;

      int jm0 = fb_j1 - 1, wl0 = jm0 / 5, sk0 = jm0 - 5 * wl0;
      if (lane == wl0) {
        usedmask = 1 << sk0;
        if      (sk0 == 0) mv0 = -INF;
        else if (sk0 == 1) mv1 = -INF;
        else if (sk0 == 2) mv2 = -INF;
        else if (sk0 == 3) mv3 = -INF;
        else               mv4 = -INF;
      }
      int o0 = __builtin_amdgcn_readlane(wp0, wl0),
          o1 = __builtin_amdgcn_readlane(wp1, wl0),
          o2 = __builtin_amdgcn_readlane(wp2, wl0),
          o3 = __builtin_amdgcn_readlane(wp3, wl0),
          o4 = __builtin_amdgcn_readlane(wp4, wl0);
      int i0u = sel5(sk0, o0 & 127, o1 & 127, o2 & 127, o3 & 127, o4 & 127);
      int j0u = fb_j1;

      while (true) {
        { int rr2 = i0u - 1; if ((rr2 & 63) == lane) uf |= 1 << (rr2 >> 6); }

        const float* rowp = costb + (i0u - 1) * NPp + laneOff;
        float fa = rowp[0], fb = rowp[1], fc = rowp[2], fd = rowp[3], fe = rowp[4];
        double ui0 = read_u_row(u_lo, u_hi, i0u);

        {
          double cur = (double)fa - ui0 - v0;
          wp0 = (cur < mv0) ? ((j0u << 7) | (wp0 & 127)) : wp0;
          mv0 = fmin(mv0, cur);
        }
        {
          double cur = (double)fb - ui0 - v1;
          wp1 = (cur < mv1) ? ((j0u << 7) | (wp1 & 127)) : wp1;
          mv1 = fmin(mv1, cur);
        }
        {
          double cur = (double)fc - ui0 - v2;
          wp2 = (cur < mv2) ? ((j0u << 7) | (wp2 & 127)) : wp2;
          mv2 = fmin(mv2, cur);
        }
        {
          double cur = (double)fd - ui0 - v3;
          wp3 = (cur < mv3) ? ((j0u << 7) | (wp3 & 127)) : wp3;
          mv3 = fmin(mv3, cur);
        }
        {
          double cur = (double)fe - ui0 - v4;
          wp4 = (cur < mv4) ? ((j0u << 7) | (wp4 & 127)) : wp4;
          mv4 = fmin(mv4, cur);
        }

        double dv0 = (!active || (usedmask & 1))  ? INF : mv0;
        double dv1 = (!active || (usedmask & 2))  ? INF : mv1;
        double dv2 = (!active || (usedmask & 4))  ? INF : mv2;
        double dv3 = (!active || (usedmask & 8))  ? INF : mv3;
        double dv4 = (!active || (usedmask & 16)) ? INF : mv4;

        double mm = fmin(fmin(fmin(dv0, dv1), fmin(dv2, dv3)), dv4);
        int kk = (dv3 == mm) ? 3 : 4;
        kk = (dv2 == mm) ? 2 : kk;
        kk = (dv1 == mm) ? 1 : kk;
        kk = (dv0 == mm) ? 0 : kk;
        int pl2 = sel5(kk, wp0 & 127, wp1 & 127, wp2 & 127, wp3 & 127, wp4 & 127);
        int pk2 = ((laneOff + kk + 1) << 7) | pl2;

        double delta2 = wave_fmin64_bcast(mm);
        unsigned long long hit2 = __ballot(mm == delta2);
        int winlane2 = __builtin_ctzll(hit2);
        int wpk2 = __builtin_amdgcn_readlane(pk2, winlane2);
        int j1b = wpk2 >> 7, i1b = wpk2 & 127;

        if (uf & 1) u_lo += delta2;
        if (uf & 2) u_hi += delta2;
        v0 -= (usedmask & 1)  ? delta2 : 0.0;
        v1 -= (usedmask & 2)  ? delta2 : 0.0;
        v2 -= (usedmask & 4)  ? delta2 : 0.0;
        v3 -= (usedmask & 8)  ? delta2 : 0.0;
        v4 -= (usedmask & 16) ? delta2 : 0.0;
        mv0 -= delta2; mv1 -= delta2; mv2 -= delta2; mv3 -= delta2; mv4 -= delta2;

        int jm = j1b - 1;
        int wl = jm / 5;
        int sk3 = jm - 5 * wl;
        if (lane == wl) {
          usedmask |= 1 << sk3;
          if      (sk3 == 0) mv0 = -INF;
          else if (sk3 == 1) mv1 = -INF;
          else if (sk3 == 2) mv2 = -INF;
          else if (sk3 == 3) mv3 = -INF;
          else               mv4 = -INF;
        }

        j0u = j1b; i0u = i1b;
        if (i0u == 0) break;
      }

      // augment alternating path (uniform readlane walk)
      {
        int jj = j0u;
        int idx = jj - 1;
        int owner = idx / 5;
        int slot = idx - 5 * owner;
        int f0 = __builtin_amdgcn_readlane(wp0, owner),
            f1 = __builtin_amdgcn_readlane(wp1, owner),
            f2 = __builtin_amdgcn_readlane(wp2, owner),
            f3 = __builtin_amdgcn_readlane(wp3, owner),
            f4 = __builtin_amdgcn_readlane(wp4, owner);
        int wpv = sel5(slot, f0, f1, f2, f3, f4);
        int wayv = wpv >> 7;

        while (true) {
          int jp = wayv;                        // uniform
          int newv;
          int wayn = 0;
          if (jp != 0) {
            int idx2 = jp - 1;
            int owner2 = idx2 / 5;
            int slot2 = idx2 - 5 * owner2;
            int g0 = __builtin_amdgcn_readlane(wp0, owner2),
                g1 = __builtin_amdgcn_readlane(wp1, owner2),
                g2 = __builtin_amdgcn_readlane(wp2, owner2),
                g3 = __builtin_amdgcn_readlane(wp3, owner2),
                g4 = __builtin_amdgcn_readlane(wp4, owner2);
            int wpn = sel5(slot2, g0, g1, g2, g3, g4);
            wayn = wpn >> 7;
            newv = wpn & 127;                   // old pj[jp]
          } else {
            newv = fbrow;
          }
          if (lane == owner) {
            if      (slot == 0) wp0 = (wp0 & ~127) | newv;
            else if (slot == 1) wp1 = (wp1 & ~127) | newv;
            else if (slot == 2) wp2 = (wp2 & ~127) | newv;
            else if (slot == 3) wp3 = (wp3 & ~127) | newv;
            else                wp4 = (wp4 & ~127) | newv;
          }
          if (jp == 0) break;
          jj = jp;
          idx = jj - 1;
          owner = idx / 5;
          slot = idx - 5 * owner;
          wayv = wayn;
        }
      }
    }

    // rebuild per-lane + uniform masks; extend S by this fallback's used-set
    occm = ((wp0 & 127) ? 1 : 0) | ((wp1 & 127) ? 2 : 0) |
           ((wp2 & 127) ? 4 : 0) | ((wp3 & 127) ? 8 : 0) |
           ((wp4 & 127) ? 16 : 0);
    M0 = __ballot(occm & 1);
    M1 = __ballot(occm & 2);
    M2 = __ballot(occm & 4);
    M3 = __ballot(occm & 8);
    M4 = __ballot(occm & 16);
    S0 |= __ballot(usedmask & 1);
    S1 |= __ballot(usedmask & 2);
    S2 |= __ballot(usedmask & 4);
    S3 |= __ballot(usedmask & 8);
    S4 |= __ballot(usedmask & 16);

    ++i;
  }

  // export assignment
  if (active) {
    int base = b * 304;
    pj_g[base + 5 * lane + 1] = wp0 & 127;
    pj_g[base + 5 * lane + 2] = wp1 & 127;
    pj_g[base + 5 * lane + 3] = wp2 & 127;
    pj_g[base + 5 * lane + 4] = wp3 & 127;
    pj_g[base + 5 * lane + 5] = wp4 & 127;
  }

  // num_predicted contribution: count cat_preds[b,1,:] < 0.5
  const float* cpb1 = cat_preds + ((size_t)b * NPp + 1) * Cc;
  float q0 = (lane < Cc) ? cpb1[lane] : 1.0f;
  float q1 = (lane + 64 < Cc) ? cpb1[lane + 64] : 1.0f;
  unsigned long long mm0 = __ballot(q0 < 0.5f);
  unsigned long long mm1 = __ballot(q1 < 0.5f);
  if (lane == 0) partials[b * 8 + 7] = (double)(__popcll(mm0) + __popcll(mm1));
}

// ---------- K3: per-column losses, one wave per (b,j) (2400 blocks) ----------

__global__ void __launch_bounds__(64) loss_kernel(
    const float* __restrict__ attribute, const float* __restrict__ bbox,
    const float* __restrict__ cat_preds, const float* __restrict__ attribute_preds,
    const float* __restrict__ box_preds, const int* __restrict__ gcls,
    const int* __restrict__ pj_g, double* __restrict__ colpart) {
  int gb = blockIdx.x;                 // b*NPp + j
  int b = gb / NPp;
  int j = gb - b * NPp;
  int lane = threadIdx.x;
  double* outp = colpart + (size_t)gb * 8;

  int prow = pj_g[b * 304 + j + 1];
  if (prow == 0) {
    if (lane < 8) outp[lane] = 0.0;
    return;
  }

  int t = prow - 1;
  int bt = b * NTt + t;

  const float EPSF = 1e-7f;
  const float HIF  = (float)(1.0 - 1e-7);

  float y = attribute[(size_t)bt * Aa + lane];
  float p = fminf(fmaxf(attribute_preds[(size_t)gb * Aa + lane], EPSF), HIF);
  float ce = -(y * logf(p) + (1.0f - y) * logf(1.0f - p));
  float pt = y * p + (1.0f - y) * (1.0f - p);
  float alpha = y * 0.25f + (1.0f - y) * 0.75f;
  float om = 1.0f - pt;
  double sattr = (double)(alpha * (om * om) * ce);
  #pragma unroll
  for (int off = 32; off >= 1; off >>= 1) sattr += __shfl_xor(sattr, off);

  if (lane == 0) {
    int cl = gcls[bt];
    float pc = cat_preds[(size_t)gb * Cc + cl];
    double scat = (double)(-logf(pc + 1e-5f));

    const float* btp = bbox + (size_t)bt * 4;
    const float* bpp = box_preds + (size_t)gb * 4;
    float iou;
    float bc = box_cost_f(btp, bpp, iou);
    float ia = 1.0f - iou;

    double c50 = (ia >= 0.5f) ? 1.0 : 0.0;
    double call = 0.0;
    for (int rr = 50; rr < 100; rr += 5) {
      float thr = (float)((double)rr / 100.0);
      if (ia >= thr) call += 1.0;
    }

    float yp = 1.0f - cat_preds[(size_t)gb * Cc + 0];
    float pn = yp / yp;
    pn = fminf(fmaxf(pn, EPSF), HIF);
    double sex = (double)(-logf(pn));

    outp[0] = scat;
    outp[1] = sattr;
    outp[2] = (double)bc;
    outp[3] = (double)ia;
    outp[4] = sex;
    outp[5] = c50;
    outp[6] = call;
    outp[7] = 0.0;
  }
}

// ---------- K4: fixed-tree per-(b,q) sums (56 blocks x 64) ----------

__global__ void __launch_bounds__(64) combine1_kernel(
    const double* __restrict__ colpart, double* __restrict__ partials) {
  int bid = blockIdx.x;                // 0..55
  int b = bid / 7;
  int q = bid - b * 7;
  int lane = threadIdx.x;

  double s = 0.0;
  #pragma unroll
  for (int k = 0; k < 5; ++k) {
    int j = lane + (k << 6);
    if (j < NPp) s += colpart[((size_t)(b * NPp + j)) * 8 + q];
  }
  #pragma unroll
  for (int off = 32; off >= 1; off >>= 1) s += __shfl_xor(s, off);
  if (lane == 0) partials[b * 8 + q] = s;
}

// ---------- K5: final outputs ----------

__global__ void final_kernel(const double* __restrict__ partials,
                             const int* __restrict__ num_objects,
                             float* __restrict__ out) {
  if (threadIdx.x != 0) return;
  double t[8];
  #pragma unroll
  for (int q = 0; q < 8; ++q) t[q] = 0.0;
  for (int b = 0; b < Bb; ++b)
    for (int q = 0; q < 8; ++q) t[q] += partials[b * 8 + q];

  int s = 0;
  for (int b = 0; b < Bb; ++b) s += num_objects[b];
  float tno = (float)s;

  float category_cost  = (float)t[0] / tno;
  float attribute_cost = (float)t[1] / tno;
  float box_cost       = (float)t[2] / tno;
  float exist_loss     = (float)t[4] / (float)(Bb * NPp);
  float total = category_cost + attribute_cost + box_cost + exist_loss;
  float iou_metric = (float)t[3] / tno;
  float npredf = (float)t[7];
  float mAP50 = (float)t[5] / npredf;
  float m5095 = (float)t[6] / (npredf * 10.0f);

  out[0] = total;
  out[1] = category_cost;
  out[2] = attribute_cost;
  out[3] = box_cost;
  out[4] = exist_loss;
  out[5] = iou_metric;
  out[6] = mAP50;
  out[7] = m5095;
}

// ---------- launcher ----------

extern "C" void kernel_launch(void* const* d_in, const int* in_sizes, int n_in,
                              void* d_out, int out_size, void* d_ws, size_t ws_size,
                              hipStream_t stream) {
  const float* category        = (const float*)d_in[0];
  const float* attribute       = (const float*)d_in[1];
  const float* bbox            = (const float*)d_in[2];
  const int*   num_objects     = (const int*)d_in[3];
  const float* cat_preds       = (const float*)d_in[4];
  const float* attribute_preds = (const float*)d_in[5];
  const float* box_preds       = (const float*)d_in[6];
  float* out = (float*)d_out;

  // ws layout
  double* partials = (double*)d_ws;                         //       0 ..     512
  int*    gcls     = (int*)((char*)d_ws + 512);             //     512 ..    3712
  float*  gcost    = (float*)((char*)d_ws + 4096);          //    4096 ..  964096
  int*    pj_g     = (int*)((char*)d_ws + 964096);          //  964096 ..  973824
  double* colpart  = (double*)((char*)d_ws + 973824);       //  973824 .. 1127424
  float*  rowminf  = (float*)((char*)d_ws + 1127424);       // 1127424 .. 1130624
  int*    rowargj  = (int*)((char*)d_ws + 1130624);         // 1130624 .. 1133824

  cost_kernel<<<Bb * NTt, 64, 0, stream>>>(category, bbox, box_preds, cat_preds,
                                           gcost, gcls, rowminf, rowargj);

  const int STAGED_LDS = NTt * NPp * 4;                     // 120000
  hipError_t e = hipFuncSetAttribute(
      reinterpret_cast<const void*>(&jv_kernel<true>),
      hipFuncAttributeMaxDynamicSharedMemorySize, STAGED_LDS);
  if (e == hipSuccess) {
    jv_kernel<true><<<Bb, 256, STAGED_LDS, stream>>>(num_objects, cat_preds,
                                                     gcost, rowminf, rowargj,
                                                     pj_g, partials);
  } else {
    jv_kernel<false><<<Bb, 256, 0, stream>>>(num_objects, cat_preds,
                                             gcost, rowminf, rowargj,
                                             pj_g, partials);
  }

  loss_kernel<<<Bb * NPp, 64, 0, stream>>>(attribute, bbox, cat_preds,
                                           attribute_preds, box_preds, gcls,
                                           pj_g, colpart);
  combine1_kernel<<<Bb * 7, 64, 0, stream>>>(colpart, partials);
  final_kernel<<<1, 64, 0, stream>>>(partials, num_objects, out);
}